// Round 8
// baseline (319.927 us; speedup 1.0000x reference)
//
#include <hip/hip_runtime.h>
#include <hip/hip_bf16.h>

// B=2, L=2048, D=1024, H=16, DH=64, M=2048
// logits[l,m] = (q[l].k[m] + (m<=l ? q[l].E[2047+m-l] : 0)) / 8, E[j]=rel[j+1]
// softmax over all m (no causal mask), out = (attn@v reshaped) @ Wo + bo
// Round 8: in-block 4-way m-split. 256-thr blocks, 4 waves x same 32 q-rows x
// disjoint 512-m chunks (additive partials, no-max softmax). Barrier-free main
// loop (per-wave T ring + P strip); 2 barriers at end for LDS merge. 8192 waves.

typedef __bf16 v8bf __attribute__((ext_vector_type(8)));
typedef __bf16 v4bf __attribute__((ext_vector_type(4)));
typedef float f32x4 __attribute__((ext_vector_type(4)));
typedef float f32x16 __attribute__((ext_vector_type(16)));

#define MFMA16(A,B,C) __builtin_amdgcn_mfma_f32_16x16x32_bf16((A),(B),(C),0,0,0)
#define MFMA32(A,B,C) __builtin_amdgcn_mfma_f32_32x32x16_bf16((A),(B),(C),0,0,0)

constexpr float kQScale = 0.1803368801111244f;   // log2(e)/8

// ---------------- rel -> E_pad [2304][64] bf16: rows 128..2175 = rel[1:2049], else 0
__global__ __launch_bounds__(256)
void cast_rel(const float* __restrict__ rel, __bf16* __restrict__ E)
{
    const int i = blockIdx.x * 256 + threadIdx.x;   // 4-elem units, 2304*16 total
    if (i >= 2304 * 16) return;
    const int base = i * 4;
    const int row = base >> 6;
    const int prow = row - 128;
    v4bf o;
    if (prow >= 0 && prow < 2048) {
        const float4 v = *reinterpret_cast<const float4*>(&rel[(size_t)(prow + 1) * 64 + (base & 63)]);
        o[0] = (__bf16)v.x; o[1] = (__bf16)v.y; o[2] = (__bf16)v.z; o[3] = (__bf16)v.w;
    } else {
        o[0] = (__bf16)0.f; o[1] = (__bf16)0.f; o[2] = (__bf16)0.f; o[3] = (__bf16)0.f;
    }
    *reinterpret_cast<v4bf*>(&E[base]) = o;
}

// ---------------- 4x W [1024][1024] fp32 -> Wt [n][k] bf16 (transpose+cast) ----------------
__global__ __launch_bounds__(256)
void transpose_cast_w4(const float* __restrict__ W0, const float* __restrict__ W1,
                       const float* __restrict__ W2, const float* __restrict__ W3,
                       __bf16* __restrict__ Wt4)
{
    __shared__ float tile[64][65];
    const int z = blockIdx.z;
    const float* W = (z == 0) ? W0 : (z == 1) ? W1 : (z == 2) ? W2 : W3;
    __bf16* Wt = Wt4 + (size_t)z * 1048576;
    const int r0 = blockIdx.y * 64, c0 = blockIdx.x * 64;
    const int tr = threadIdx.x >> 4;
    const int tc = (threadIdx.x & 15) * 4;
    #pragma unroll
    for (int p = 0; p < 4; ++p) {
        const int r = tr + p * 16;
        const float4 v = *reinterpret_cast<const float4*>(&W[(size_t)(r0 + r) * 1024 + c0 + tc]);
        tile[r][tc + 0] = v.x; tile[r][tc + 1] = v.y; tile[r][tc + 2] = v.z; tile[r][tc + 3] = v.w;
    }
    __syncthreads();
    #pragma unroll
    for (int p = 0; p < 4; ++p) {
        const int cr = tr + p * 16;
        v4bf o;
        o[0] = (__bf16)tile[tc + 0][cr];
        o[1] = (__bf16)tile[tc + 1][cr];
        o[2] = (__bf16)tile[tc + 2][cr];
        o[3] = (__bf16)tile[tc + 3][cr];
        *reinterpret_cast<v4bf*>(&Wt[(size_t)(c0 + cr) * 1024 + r0 + tc]) = o;
    }
}

// ---------------- bf16 MFMA GEMM body: C = A[4096x1024] @ Wt^T + bias ----------------
// mode 0: fp32 flat out; mode 1: bf16 heads [bh][l][64] (scaled by oscale);
// mode 2: bf16 [bh][dh][2048]
template <bool ABF16>
__device__ __forceinline__
void gemm_body(const float* __restrict__ Af, const __bf16* __restrict__ Ab,
               const __bf16* __restrict__ Wt, const float* __restrict__ bias,
               float* __restrict__ Cf, __bf16* __restrict__ Cb, int mode,
               float oscale, int bx, int by)
{
    __shared__ __bf16 As[2][128 * 64];
    __shared__ __bf16 Ws[2][64 * 64];
    const int tid = threadIdx.x;
    const int wid = tid >> 6, lane = tid & 63, g = lane >> 4, li = lane & 15;
    const int r0 = by * 128, c0 = bx * 64;
    const int wr = wid >> 1, wc = wid & 1;
    const int sr = tid >> 3, sb = tid & 7;

    f32x4 acc[4][2];
    #pragma unroll
    for (int a = 0; a < 4; ++a)
        #pragma unroll
        for (int b2 = 0; b2 < 2; ++b2) acc[a][b2] = f32x4{0.f, 0.f, 0.f, 0.f};

    v8bf areg[4], wreg[2];

    auto loadA = [&](int p, int kt) -> v8bf {
        if constexpr (ABF16) {
            return *reinterpret_cast<const v8bf*>(&Ab[(size_t)(r0 + sr + 32 * p) * 1024 + kt + sb * 8]);
        } else {
            const float* ar = &Af[(size_t)(r0 + sr + 32 * p) * 1024 + kt + sb * 8];
            const float4 f0 = *reinterpret_cast<const float4*>(ar);
            const float4 f1 = *reinterpret_cast<const float4*>(ar + 4);
            v8bf a8;
            a8[0] = (__bf16)f0.x; a8[1] = (__bf16)f0.y; a8[2] = (__bf16)f0.z; a8[3] = (__bf16)f0.w;
            a8[4] = (__bf16)f1.x; a8[5] = (__bf16)f1.y; a8[6] = (__bf16)f1.z; a8[7] = (__bf16)f1.w;
            return a8;
        }
    };

    #pragma unroll
    for (int p = 0; p < 4; ++p) areg[p] = loadA(p, 0);
    #pragma unroll
    for (int p = 0; p < 2; ++p)
        wreg[p] = *reinterpret_cast<const v8bf*>(&Wt[(size_t)(c0 + sr + 32 * p) * 1024 + sb * 8]);
    #pragma unroll
    for (int p = 0; p < 4; ++p) {
        const int row = sr + 32 * p;
        *reinterpret_cast<v8bf*>(&As[0][row * 64 + ((sb ^ (row & 7)) << 3)]) = areg[p];
    }
    #pragma unroll
    for (int p = 0; p < 2; ++p) {
        const int row = sr + 32 * p;
        *reinterpret_cast<v8bf*>(&Ws[0][row * 64 + ((sb ^ (row & 7)) << 3)]) = wreg[p];
    }
    __syncthreads();

    for (int ki = 0; ki < 16; ++ki) {
        const int cur = ki & 1;
        if (ki < 15) {
            const int kt = (ki + 1) * 64;
            #pragma unroll
            for (int p = 0; p < 4; ++p) areg[p] = loadA(p, kt);
            #pragma unroll
            for (int p = 0; p < 2; ++p)
                wreg[p] = *reinterpret_cast<const v8bf*>(&Wt[(size_t)(c0 + sr + 32 * p) * 1024 + kt + sb * 8]);
        }
        #pragma unroll
        for (int ks = 0; ks < 2; ++ks) {
            v8bf af[4], bfr[2];
            #pragma unroll
            for (int fm = 0; fm < 4; ++fm) {
                const int row = wr * 64 + fm * 16 + li;
                af[fm] = *reinterpret_cast<const v8bf*>(
                    &As[cur][row * 64 + (((ks * 4 + g) ^ (row & 7)) << 3)]);
            }
            #pragma unroll
            for (int fn = 0; fn < 2; ++fn) {
                const int row = wc * 32 + fn * 16 + li;
                bfr[fn] = *reinterpret_cast<const v8bf*>(
                    &Ws[cur][row * 64 + (((ks * 4 + g) ^ (row & 7)) << 3)]);
            }
            __builtin_amdgcn_s_setprio(1);
            #pragma unroll
            for (int fm = 0; fm < 4; ++fm)
                #pragma unroll
                for (int fn = 0; fn < 2; ++fn)
                    acc[fm][fn] = MFMA16(af[fm], bfr[fn], acc[fm][fn]);
            __builtin_amdgcn_s_setprio(0);
        }
        if (ki < 15) {
            const int nxt = cur ^ 1;
            #pragma unroll
            for (int p = 0; p < 4; ++p) {
                const int row = sr + 32 * p;
                *reinterpret_cast<v8bf*>(&As[nxt][row * 64 + ((sb ^ (row & 7)) << 3)]) = areg[p];
            }
            #pragma unroll
            for (int p = 0; p < 2; ++p) {
                const int row = sr + 32 * p;
                *reinterpret_cast<v8bf*>(&Ws[nxt][row * 64 + ((sb ^ (row & 7)) << 3)]) = wreg[p];
            }
        }
        __syncthreads();
    }

    #pragma unroll
    for (int fn = 0; fn < 2; ++fn) {
        const int col = c0 + wc * 32 + fn * 16 + li;
        const float bb = bias[col];
        #pragma unroll
        for (int fm = 0; fm < 4; ++fm) {
            if (mode == 2) {
                const int row = r0 + wr * 64 + fm * 16 + 4 * g;
                const int b = row >> 11, l = row & 2047;
                const int h = col >> 6, dh = col & 63;
                v4bf pk;
                #pragma unroll
                for (int reg = 0; reg < 4; ++reg)
                    pk[reg] = (__bf16)(acc[fm][fn][reg] + bb);
                *reinterpret_cast<v4bf*>(&Cb[((size_t)((b * 16 + h) * 64 + dh)) * 2048 + l]) = pk;
            } else {
                #pragma unroll
                for (int reg = 0; reg < 4; ++reg) {
                    const int row = r0 + wr * 64 + fm * 16 + 4 * g + reg;
                    const float val = acc[fm][fn][reg] + bb;
                    if (mode == 0) {
                        Cf[(size_t)row * 1024 + col] = val;
                    } else {
                        const int b = row >> 11, l = row & 2047, h = col >> 6, dh = col & 63;
                        Cb[((size_t)(b * 16 + h) * 2048 + l) * 64 + dh] = (__bf16)(val * oscale);
                    }
                }
            }
        }
    }
}

__global__ __launch_bounds__(256)
void gemm_proj3(const float* __restrict__ Aq, const float* __restrict__ Ak,
                const float* __restrict__ Av, const __bf16* __restrict__ Wt4,
                const float* __restrict__ bq, const float* __restrict__ bk,
                const float* __restrict__ bv, __bf16* __restrict__ qo,
                __bf16* __restrict__ ko, __bf16* __restrict__ vto)
{
    const int z = blockIdx.z;
    const float* A = (z == 0) ? Aq : (z == 1) ? Ak : Av;
    const __bf16* Wt = Wt4 + (size_t)z * 1048576;
    const float* bias = (z == 0) ? bq : (z == 1) ? bk : bv;
    __bf16* Cb = (z == 0) ? qo : (z == 1) ? ko : vto;
    const float osc = (z == 0) ? kQScale : 1.0f;
    gemm_body<false>(A, nullptr, Wt, bias, nullptr, Cb, (z == 2) ? 2 : 1, osc,
                     blockIdx.x, blockIdx.y);
}

__global__ __launch_bounds__(256)
void gemm_out(const __bf16* __restrict__ A, const __bf16* __restrict__ Wt,
              const float* __restrict__ bias, float* __restrict__ C)
{
    gemm_body<true>(nullptr, A, Wt, bias, C, nullptr, 0, 1.0f, blockIdx.x, blockIdx.y);
}

// ---------------- fused attention: in-block 4-way m-split ----------------
// q,k: [32][2048][64] bf16 (q prescaled); vt: [32][64][2048] bf16;
// Ep: padded E (rows -128..2175 valid); ao: [4096][1024] bf16.
// Block = 256 thr = 4 waves; all waves share 32 q-rows, wave w handles
// m in [w*512, w*512+512) (8 t-steps). Additive partials merged via LDS.
__global__ __launch_bounds__(256, 4)
void attn_mfma(const __bf16* __restrict__ q, const __bf16* __restrict__ k,
               const __bf16* __restrict__ vt, const __bf16* __restrict__ Ep,
               __bf16* __restrict__ ao)
{
    // per-wave: T ring 32*132*2 = 8448 B, P strip 32*72*2 = 4608 B -> 13056 B
    // merge alias: O partials 4*32*68*4 = 34816 B + lsum 512 B  (<= 52224)
    __shared__ __align__(16) char smem[52224 + 512];

    const int tid = threadIdx.x;
    const int wid = tid >> 6;
    const int lane = tid & 63;
    const int l31 = lane & 31;
    const int g2 = (lane >> 5) & 1;

    __bf16* Tw = (__bf16*)(smem + wid * 13056);
    __bf16* Pw = (__bf16*)(smem + wid * 13056 + 8448);

    // XCD-aware remap: 4 bh per XCD, all 64 row-groups of a bh on one XCD
    const int flat = blockIdx.x;
    const int xcd = flat & 7;
    const int idx = flat >> 3;
    const int bh = xcd * 4 + (idx >> 6);
    const int lw0 = (idx & 63) * 32;

    const size_t hbase = (size_t)bh * (2048 * 64);
    const __bf16* qp = q + hbase;
    const __bf16* kp = k + hbase;
    const __bf16* vtp = vt + hbase;
    const int wb0 = 1984 - lw0;           // e-window base at t=0 (can be -32)

    // Q B-fragments (col = l lane-local); prescaled by log2e/8 at projection
    v8bf qf[4];
    {
        const __bf16* qrow = qp + (size_t)(lw0 + l31) * 64 + g2 * 8;
        qf[0] = *reinterpret_cast<const v8bf*>(qrow);
        qf[1] = *reinterpret_cast<const v8bf*>(qrow + 16);
        qf[2] = *reinterpret_cast<const v8bf*>(qrow + 32);
        qf[3] = *reinterpret_cast<const v8bf*>(qrow + 48);
    }

    auto eload = [&](int baseRow, v8bf eb[8]) {
        #pragma unroll
        for (int jc = 0; jc < 2; ++jc)
            #pragma unroll
            for (int ks = 0; ks < 4; ++ks)
                eb[jc * 4 + ks] = *reinterpret_cast<const v8bf*>(
                    Ep + (long)(baseRow + jc * 32 + l31) * 64 + ks * 16 + g2 * 8);
    };

    // T-GEMM: D[j = E-row][l]: lane holds col l31; rows j = (reg&3)+8*(reg>>2)+4*g2
    auto tgemm = [&](const v8bf eb[8], int colBase) {
        #pragma unroll
        for (int jc = 0; jc < 2; ++jc) {
            f32x16 tacc;
            #pragma unroll
            for (int r = 0; r < 16; ++r) tacc[r] = 0.f;
            __builtin_amdgcn_s_setprio(1);
            #pragma unroll
            for (int ks = 0; ks < 4; ++ks)
                tacc = MFMA32(eb[jc * 4 + ks], qf[ks], tacc);
            __builtin_amdgcn_s_setprio(0);
            #pragma unroll
            for (int r2 = 0; r2 < 4; ++r2) {
                v4bf w;
                w[0] = (__bf16)tacc[4 * r2 + 0]; w[1] = (__bf16)tacc[4 * r2 + 1];
                w[2] = (__bf16)tacc[4 * r2 + 2]; w[3] = (__bf16)tacc[4 * r2 + 3];
                *reinterpret_cast<v4bf*>(
                    &Tw[l31 * 132 + colBase + jc * 32 + 8 * r2 + 4 * g2]) = w;
            }
        }
    };

    const int t0 = wid * 8, t1 = t0 + 8;      // this wave's m-chunk
    const bool chunkRel = (t0 * 64 <= lw0 + 31);

    // prologue: T window [wb0 + 512*wid, +128) -- only if chunk touches the band
    if (chunkRel) {
        v8bf ebA[8], ebB[8];
        eload(wb0 + 512 * wid, ebA);
        eload(wb0 + 512 * wid + 64, ebB);
        tgemm(ebA, 0);
        tgemm(ebB, 64);
    }

    f32x16 oacc[2];
    #pragma unroll
    for (int dc = 0; dc < 2; ++dc)
        #pragma unroll
        for (int r = 0; r < 16; ++r) oacc[dc][r] = 0.f;
    float lrow = 0.f;

    for (int t = t0; t < t1; ++t) {
        const int m0 = t * 64;
        const bool needRel = (m0 <= lw0 + 31);
        const bool fullAdd = (m0 + 63 <= lw0);
        const bool needTnext = (m0 + 64 <= lw0 + 31) && (t + 1 < t1);
        const int lob = 64 * (t & 1);         // t0 even -> same parity as (t-t0)

        // E loads for next T block (early issue)
        v8bf ebN[8];
        if (needTnext) eload(wb0 + m0 + 128, ebN);

        // V A-frags direct from global (consumed at end of step)
        v8bf vb0[4], vb1[4];
        #pragma unroll
        for (int ks = 0; ks < 4; ++ks) {
            vb0[ks] = *reinterpret_cast<const v8bf*>(
                vtp + (size_t)(l31) * 2048 + m0 + ks * 16 + g2 * 8);
            vb1[ks] = *reinterpret_cast<const v8bf*>(
                vtp + (size_t)(32 + l31) * 2048 + m0 + ks * 16 + g2 * 8);
        }

        #pragma unroll
        for (int mc = 0; mc < 2; ++mc) {
            // K A-frags direct from global
            v8bf kb[4];
            #pragma unroll
            for (int ks = 0; ks < 4; ++ks)
                kb[ks] = *reinterpret_cast<const v8bf*>(
                    kp + (size_t)(m0 + mc * 32 + l31) * 64 + ks * 16 + g2 * 8);

            f32x16 sacc;
            #pragma unroll
            for (int r = 0; r < 16; ++r) sacc[r] = 0.f;
            __builtin_amdgcn_s_setprio(1);
            #pragma unroll
            for (int ks = 0; ks < 4; ++ks)
                sacc = MFMA32(kb[ks], qf[ks], sacc);
            __builtin_amdgcn_s_setprio(0);

            // rel gather from T ring (lane-local row l31)
            if (needRel) {
                const int cb = 63 - l31 + lob;
                if (fullAdd) {
                    #pragma unroll
                    for (int r2 = 0; r2 < 4; ++r2)
                        #pragma unroll
                        for (int i2 = 0; i2 < 4; ++i2) {
                            const int mtl = mc * 32 + 8 * r2 + 4 * g2 + i2;
                            const int c = (cb + mtl) & 127;
                            sacc[4 * r2 + i2] += (float)Tw[l31 * 132 + c];
                        }
                } else {
                    const int R = lw0 + l31 - m0;          // add iff mtl <= R
                    #pragma unroll
                    for (int r2 = 0; r2 < 4; ++r2)
                        #pragma unroll
                        for (int i2 = 0; i2 < 4; ++i2) {
                            const int mtl = mc * 32 + 8 * r2 + 4 * g2 + i2;
                            const int c = (cb + mtl) & 127;
                            const float tv = (float)Tw[l31 * 132 + c];
                            sacc[4 * r2 + i2] += (mtl <= R) ? tv : 0.f;
                        }
                }
            }

            // exp2 + row-sum + P write to per-wave LDS (verified layout:
            // row l31, col m = mc*32 + 8*r2 + 4*g2 + i2)
            #pragma unroll
            for (int r2 = 0; r2 < 4; ++r2) {
                const float p0 = exp2f(sacc[4 * r2 + 0]);
                const float p1 = exp2f(sacc[4 * r2 + 1]);
                const float p2 = exp2f(sacc[4 * r2 + 2]);
                const float p3 = exp2f(sacc[4 * r2 + 3]);
                lrow += (p0 + p1) + (p2 + p3);
                v4bf w;
                w[0] = (__bf16)p0; w[1] = (__bf16)p1; w[2] = (__bf16)p2; w[3] = (__bf16)p3;
                *reinterpret_cast<v4bf*>(&Pw[l31 * 72 + mc * 32 + 8 * r2 + 4 * g2]) = w;
            }
        }

        // new-hi T block for t+1 (after gathers read the retiring lo half)
        if (needTnext) tgemm(ebN, lob);

        // PV: B-frag read from Pw (verified: row l31, k = ks*16 + g2*8)
        #pragma unroll
        for (int ks = 0; ks < 4; ++ks) {
            const v8bf pf = *reinterpret_cast<const v8bf*>(&Pw[l31 * 72 + ks * 16 + g2 * 8]);
            __builtin_amdgcn_s_setprio(1);
            oacc[0] = MFMA32(vb0[ks], pf, oacc[0]);
            oacc[1] = MFMA32(vb1[ks], pf, oacc[1]);
            __builtin_amdgcn_s_setprio(0);
        }
    }

    // ---- merge partials across the 4 waves via LDS ----
    lrow += __shfl_xor(lrow, 32);             // combine g2 halves (same q-row)

    __syncthreads();                          // all waves done with T/P regions
    float* Op = (float*)smem;                 // [4][32][68] fp32
    float* Ls = (float*)(smem + 34816);       // [4][32]
    #pragma unroll
    for (int dc = 0; dc < 2; ++dc)
        #pragma unroll
        for (int r2 = 0; r2 < 4; ++r2) {
            f32x4 wv;
            wv[0] = oacc[dc][4 * r2 + 0]; wv[1] = oacc[dc][4 * r2 + 1];
            wv[2] = oacc[dc][4 * r2 + 2]; wv[3] = oacc[dc][4 * r2 + 3];
            *reinterpret_cast<f32x4*>(
                &Op[(wid * 32 + l31) * 68 + dc * 32 + 8 * r2 + 4 * g2]) = wv;
        }
    if (lane < 32) Ls[wid * 32 + l31] = lrow;
    __syncthreads();

    // merge + store: thread (r = tid>>3, oct = tid&7) handles 8 d's of q-row r
    {
        const int r = tid >> 3, oct = tid & 7;
        const float lt = Ls[r] + Ls[32 + r] + Ls[64 + r] + Ls[96 + r];
        const float inv = 1.0f / lt;
        f32x4 s0 = {0.f, 0.f, 0.f, 0.f}, s1 = {0.f, 0.f, 0.f, 0.f};
        #pragma unroll
        for (int w = 0; w < 4; ++w) {
            const float* src = &Op[(w * 32 + r) * 68 + oct * 8];
            const f32x4 a = *reinterpret_cast<const f32x4*>(src);
            const f32x4 b4 = *reinterpret_cast<const f32x4*>(src + 4);
            s0 += a; s1 += b4;
        }
        v8bf o8;
        o8[0] = (__bf16)(s0[0] * inv); o8[1] = (__bf16)(s0[1] * inv);
        o8[2] = (__bf16)(s0[2] * inv); o8[3] = (__bf16)(s0[3] * inv);
        o8[4] = (__bf16)(s1[0] * inv); o8[5] = (__bf16)(s1[1] * inv);
        o8[6] = (__bf16)(s1[2] * inv); o8[7] = (__bf16)(s1[3] * inv);
        const int b = bh >> 4, h = bh & 15;
        *reinterpret_cast<v8bf*>(
            ao + (size_t)(b * 2048 + lw0 + r) * 1024 + h * 64 + oct * 8) = o8;
    }
}

extern "C" void kernel_launch(void* const* d_in, const int* in_sizes, int n_in,
                              void* d_out, int out_size, void* d_ws, size_t ws_size,
                              hipStream_t stream) {
    (void)in_sizes; (void)n_in; (void)out_size; (void)ws_size;
    const float* query = (const float*)d_in[0];
    const float* key   = (const float*)d_in[1];
    const float* value = (const float*)d_in[2];
    const float* Wq    = (const float*)d_in[3];
    const float* bq    = (const float*)d_in[4];
    const float* Wk    = (const float*)d_in[5];
    const float* bk    = (const float*)d_in[6];
    const float* Wv    = (const float*)d_in[7];
    const float* bv    = (const float*)d_in[8];
    const float* Wo    = (const float*)d_in[9];
    const float* bo    = (const float*)d_in[10];
    const float* rel   = (const float*)d_in[11];
    float* out = (float*)d_out;

    __bf16* q_bf  = (__bf16*)d_ws;            // [32][2048][64]   8 MiB (prescaled)
    __bf16* k_bf  = q_bf + 4194304;           //                  8 MiB
    __bf16* vt_bf = k_bf + 4194304;           // [32][64][2048]   8 MiB
    __bf16* Wt4   = vt_bf + 4194304;          // 4x [1024][1024]  8 MiB
    __bf16* E_pad = Wt4 + 4194304;            // [2304][64]       0.28 MiB
    __bf16* aob   = E_pad + 147456;           // [4096][1024]     8 MiB

    const dim3 blk(256);

    cast_rel<<<144, blk, 0, stream>>>(rel, E_pad);
    transpose_cast_w4<<<dim3(16, 16, 4), blk, 0, stream>>>(Wq, Wk, Wv, Wo, Wt4);
    gemm_proj3<<<dim3(16, 32, 3), blk, 0, stream>>>(query, key, value, Wt4,
                                                    bq, bk, bv, q_bf, k_bf, vt_bf);
    attn_mfma<<<dim3(2048), blk, 0, stream>>>(q_bf, k_bf, vt_bf,
                                              E_pad + 128 * 64, aob);
    gemm_out<<<dim3(16, 32), blk, 0, stream>>>(aob, Wt4 + 3 * 1048576, bo, out);
}

// Round 9
// 300.850 us; speedup vs baseline: 1.0634x; 1.0634x over previous
//
#include <hip/hip_runtime.h>
#include <hip/hip_bf16.h>

// B=2, L=2048, D=1024, H=16, DH=64, M=2048
// logits[l,m] = (q[l].k[m] + (m<=l ? q[l].E[2047+m-l] : 0)) / 8, E[j]=rel[j+1]
// softmax over all m (no causal mask), out = (attn@v reshaped) @ Wo + bo
// Round 9: revert to round-4 verified attention structure (122us), plus:
//  - conflict-free LDS strides: T ring 132->130 (bank step 1), P strip 72->66
//  - q prescaled by log2(e)/8 in projection (removes in-loop scale)

typedef __bf16 v8bf __attribute__((ext_vector_type(8)));
typedef __bf16 v4bf __attribute__((ext_vector_type(4)));
typedef float f32x4 __attribute__((ext_vector_type(4)));
typedef float f32x16 __attribute__((ext_vector_type(16)));

#define MFMA16(A,B,C) __builtin_amdgcn_mfma_f32_16x16x32_bf16((A),(B),(C),0,0,0)
#define MFMA32(A,B,C) __builtin_amdgcn_mfma_f32_32x32x16_bf16((A),(B),(C),0,0,0)

constexpr float kQScale = 0.1803368801111244f;   // log2(e)/8

// ---------------- rel -> E_pad [2304][64] bf16: rows 128..2175 = rel[1:2049], else 0
__global__ __launch_bounds__(256)
void cast_rel(const float* __restrict__ rel, __bf16* __restrict__ E)
{
    const int i = blockIdx.x * 256 + threadIdx.x;   // 4-elem units, 2304*16 total
    if (i >= 2304 * 16) return;
    const int base = i * 4;
    const int row = base >> 6;
    const int prow = row - 128;
    v4bf o;
    if (prow >= 0 && prow < 2048) {
        const float4 v = *reinterpret_cast<const float4*>(&rel[(size_t)(prow + 1) * 64 + (base & 63)]);
        o[0] = (__bf16)v.x; o[1] = (__bf16)v.y; o[2] = (__bf16)v.z; o[3] = (__bf16)v.w;
    } else {
        o[0] = (__bf16)0.f; o[1] = (__bf16)0.f; o[2] = (__bf16)0.f; o[3] = (__bf16)0.f;
    }
    *reinterpret_cast<v4bf*>(&E[base]) = o;
}

// ---------------- 4x W [1024][1024] fp32 -> Wt [n][k] bf16 (transpose+cast) ----------------
__global__ __launch_bounds__(256)
void transpose_cast_w4(const float* __restrict__ W0, const float* __restrict__ W1,
                       const float* __restrict__ W2, const float* __restrict__ W3,
                       __bf16* __restrict__ Wt4)
{
    __shared__ float tile[64][65];
    const int z = blockIdx.z;
    const float* W = (z == 0) ? W0 : (z == 1) ? W1 : (z == 2) ? W2 : W3;
    __bf16* Wt = Wt4 + (size_t)z * 1048576;
    const int r0 = blockIdx.y * 64, c0 = blockIdx.x * 64;
    const int tr = threadIdx.x >> 4;
    const int tc = (threadIdx.x & 15) * 4;
    #pragma unroll
    for (int p = 0; p < 4; ++p) {
        const int r = tr + p * 16;
        const float4 v = *reinterpret_cast<const float4*>(&W[(size_t)(r0 + r) * 1024 + c0 + tc]);
        tile[r][tc + 0] = v.x; tile[r][tc + 1] = v.y; tile[r][tc + 2] = v.z; tile[r][tc + 3] = v.w;
    }
    __syncthreads();
    #pragma unroll
    for (int p = 0; p < 4; ++p) {
        const int cr = tr + p * 16;
        v4bf o;
        o[0] = (__bf16)tile[tc + 0][cr];
        o[1] = (__bf16)tile[tc + 1][cr];
        o[2] = (__bf16)tile[tc + 2][cr];
        o[3] = (__bf16)tile[tc + 3][cr];
        *reinterpret_cast<v4bf*>(&Wt[(size_t)(c0 + cr) * 1024 + r0 + tc]) = o;
    }
}

// ---------------- bf16 MFMA GEMM body: C = A[4096x1024] @ Wt^T + bias ----------------
// mode 0: fp32 flat out; mode 1: bf16 heads [bh][l][64] (scaled by oscale);
// mode 2: bf16 [bh][dh][2048]
template <bool ABF16>
__device__ __forceinline__
void gemm_body(const float* __restrict__ Af, const __bf16* __restrict__ Ab,
               const __bf16* __restrict__ Wt, const float* __restrict__ bias,
               float* __restrict__ Cf, __bf16* __restrict__ Cb, int mode,
               float oscale, int bx, int by)
{
    __shared__ __bf16 As[2][128 * 64];
    __shared__ __bf16 Ws[2][64 * 64];
    const int tid = threadIdx.x;
    const int wid = tid >> 6, lane = tid & 63, g = lane >> 4, li = lane & 15;
    const int r0 = by * 128, c0 = bx * 64;
    const int wr = wid >> 1, wc = wid & 1;
    const int sr = tid >> 3, sb = tid & 7;

    f32x4 acc[4][2];
    #pragma unroll
    for (int a = 0; a < 4; ++a)
        #pragma unroll
        for (int b2 = 0; b2 < 2; ++b2) acc[a][b2] = f32x4{0.f, 0.f, 0.f, 0.f};

    v8bf areg[4], wreg[2];

    auto loadA = [&](int p, int kt) -> v8bf {
        if constexpr (ABF16) {
            return *reinterpret_cast<const v8bf*>(&Ab[(size_t)(r0 + sr + 32 * p) * 1024 + kt + sb * 8]);
        } else {
            const float* ar = &Af[(size_t)(r0 + sr + 32 * p) * 1024 + kt + sb * 8];
            const float4 f0 = *reinterpret_cast<const float4*>(ar);
            const float4 f1 = *reinterpret_cast<const float4*>(ar + 4);
            v8bf a8;
            a8[0] = (__bf16)f0.x; a8[1] = (__bf16)f0.y; a8[2] = (__bf16)f0.z; a8[3] = (__bf16)f0.w;
            a8[4] = (__bf16)f1.x; a8[5] = (__bf16)f1.y; a8[6] = (__bf16)f1.z; a8[7] = (__bf16)f1.w;
            return a8;
        }
    };

    #pragma unroll
    for (int p = 0; p < 4; ++p) areg[p] = loadA(p, 0);
    #pragma unroll
    for (int p = 0; p < 2; ++p)
        wreg[p] = *reinterpret_cast<const v8bf*>(&Wt[(size_t)(c0 + sr + 32 * p) * 1024 + sb * 8]);
    #pragma unroll
    for (int p = 0; p < 4; ++p) {
        const int row = sr + 32 * p;
        *reinterpret_cast<v8bf*>(&As[0][row * 64 + ((sb ^ (row & 7)) << 3)]) = areg[p];
    }
    #pragma unroll
    for (int p = 0; p < 2; ++p) {
        const int row = sr + 32 * p;
        *reinterpret_cast<v8bf*>(&Ws[0][row * 64 + ((sb ^ (row & 7)) << 3)]) = wreg[p];
    }
    __syncthreads();

    for (int ki = 0; ki < 16; ++ki) {
        const int cur = ki & 1;
        if (ki < 15) {
            const int kt = (ki + 1) * 64;
            #pragma unroll
            for (int p = 0; p < 4; ++p) areg[p] = loadA(p, kt);
            #pragma unroll
            for (int p = 0; p < 2; ++p)
                wreg[p] = *reinterpret_cast<const v8bf*>(&Wt[(size_t)(c0 + sr + 32 * p) * 1024 + kt + sb * 8]);
        }
        #pragma unroll
        for (int ks = 0; ks < 2; ++ks) {
            v8bf af[4], bfr[2];
            #pragma unroll
            for (int fm = 0; fm < 4; ++fm) {
                const int row = wr * 64 + fm * 16 + li;
                af[fm] = *reinterpret_cast<const v8bf*>(
                    &As[cur][row * 64 + (((ks * 4 + g) ^ (row & 7)) << 3)]);
            }
            #pragma unroll
            for (int fn = 0; fn < 2; ++fn) {
                const int row = wc * 32 + fn * 16 + li;
                bfr[fn] = *reinterpret_cast<const v8bf*>(
                    &Ws[cur][row * 64 + (((ks * 4 + g) ^ (row & 7)) << 3)]);
            }
            __builtin_amdgcn_s_setprio(1);
            #pragma unroll
            for (int fm = 0; fm < 4; ++fm)
                #pragma unroll
                for (int fn = 0; fn < 2; ++fn)
                    acc[fm][fn] = MFMA16(af[fm], bfr[fn], acc[fm][fn]);
            __builtin_amdgcn_s_setprio(0);
        }
        if (ki < 15) {
            const int nxt = cur ^ 1;
            #pragma unroll
            for (int p = 0; p < 4; ++p) {
                const int row = sr + 32 * p;
                *reinterpret_cast<v8bf*>(&As[nxt][row * 64 + ((sb ^ (row & 7)) << 3)]) = areg[p];
            }
            #pragma unroll
            for (int p = 0; p < 2; ++p) {
                const int row = sr + 32 * p;
                *reinterpret_cast<v8bf*>(&Ws[nxt][row * 64 + ((sb ^ (row & 7)) << 3)]) = wreg[p];
            }
        }
        __syncthreads();
    }

    #pragma unroll
    for (int fn = 0; fn < 2; ++fn) {
        const int col = c0 + wc * 32 + fn * 16 + li;
        const float bb = bias[col];
        #pragma unroll
        for (int fm = 0; fm < 4; ++fm) {
            if (mode == 2) {
                const int row = r0 + wr * 64 + fm * 16 + 4 * g;
                const int b = row >> 11, l = row & 2047;
                const int h = col >> 6, dh = col & 63;
                v4bf pk;
                #pragma unroll
                for (int reg = 0; reg < 4; ++reg)
                    pk[reg] = (__bf16)(acc[fm][fn][reg] + bb);
                *reinterpret_cast<v4bf*>(&Cb[((size_t)((b * 16 + h) * 64 + dh)) * 2048 + l]) = pk;
            } else {
                #pragma unroll
                for (int reg = 0; reg < 4; ++reg) {
                    const int row = r0 + wr * 64 + fm * 16 + 4 * g + reg;
                    const float val = acc[fm][fn][reg] + bb;
                    if (mode == 0) {
                        Cf[(size_t)row * 1024 + col] = val;
                    } else {
                        const int b = row >> 11, l = row & 2047, h = col >> 6, dh = col & 63;
                        Cb[((size_t)(b * 16 + h) * 2048 + l) * 64 + dh] = (__bf16)(val * oscale);
                    }
                }
            }
        }
    }
}

__global__ __launch_bounds__(256)
void gemm_proj3(const float* __restrict__ Aq, const float* __restrict__ Ak,
                const float* __restrict__ Av, const __bf16* __restrict__ Wt4,
                const float* __restrict__ bq, const float* __restrict__ bk,
                const float* __restrict__ bv, __bf16* __restrict__ qo,
                __bf16* __restrict__ ko, __bf16* __restrict__ vto)
{
    const int z = blockIdx.z;
    const float* A = (z == 0) ? Aq : (z == 1) ? Ak : Av;
    const __bf16* Wt = Wt4 + (size_t)z * 1048576;
    const float* bias = (z == 0) ? bq : (z == 1) ? bk : bv;
    __bf16* Cb = (z == 0) ? qo : (z == 1) ? ko : vto;
    const float osc = (z == 0) ? kQScale : 1.0f;
    gemm_body<false>(A, nullptr, Wt, bias, nullptr, Cb, (z == 2) ? 2 : 1, osc,
                     blockIdx.x, blockIdx.y);
}

__global__ __launch_bounds__(256)
void gemm_out(const __bf16* __restrict__ A, const __bf16* __restrict__ Wt,
              const float* __restrict__ bias, float* __restrict__ C)
{
    gemm_body<true>(nullptr, A, Wt, bias, C, nullptr, 0, 1.0f, blockIdx.x, blockIdx.y);
}

// ---------------- fused attention: 32x32 MFMA, swapped operands (round-4 base) ----------------
// q,k: [32][2048][64] bf16 (q prescaled); vt: [32][64][2048] bf16;
// Ep: padded E (rows -128..2175 valid); ao: [4096][1024] bf16.
// Block = 256 thr = 4 waves x 32 q-rows; 32 m-steps of 64; K/V staged in shared
// LDS (single-buffer, reg prefetch, 2 barriers/step); per-wave T ring (stride
// 130, conflict-free) and P strip (stride 66, conflict-free).
__global__ __launch_bounds__(256, 2)
void attn_mfma(const __bf16* __restrict__ q, const __bf16* __restrict__ k,
               const __bf16* __restrict__ vt, const __bf16* __restrict__ Ep,
               __bf16* __restrict__ ao)
{
    __shared__ __bf16 Kl[64 * 64];        // [m][d], 16B-block XOR swizzle (8K)
    __shared__ __bf16 Vl[64 * 64];        // [d][m], swizzled (8K)
    __shared__ __bf16 Tl[4][32 * 130];    // per-wave T window [32 rows][128+2] (32.5K)
    __shared__ __bf16 Pl[4][32 * 66];     // per-wave P [32 rows][64+2] (16.5K)

    const int tid = threadIdx.x;
    const int wid = tid >> 6;
    const int lane = tid & 63;
    const int l31 = lane & 31;
    const int g2 = lane >> 5;

    // XCD-aware remap: all 16 q-tiles of a bh land on one XCD (K/V L2 locality)
    const int flat = blockIdx.y * 16 + blockIdx.x;
    const int jj_ = flat >> 3;
    const int bh = (flat & 7) * 4 + (jj_ >> 4);
    const int qt = jj_ & 15;

    const int l0 = qt * 128;
    const int lw0 = l0 + wid * 32;            // wave's first q-row
    const size_t hbase = (size_t)bh * (2048 * 64);
    const __bf16* qp = q + hbase;
    const __bf16* kp = k + hbase;
    const __bf16* vtp = vt + hbase;           // [64][2048]
    const int wb0 = 1984 - lw0;               // per-wave e-window base at t=0

    __bf16* Tw = &Tl[wid][0];
    __bf16* Pw = &Pl[wid][0];

    // Q B-fragments (col = l lane-local), prescaled by log2e/8 at projection
    v8bf qf[4];
    {
        const __bf16* qrow = qp + (size_t)(lw0 + l31) * 64 + g2 * 8;
        qf[0] = *reinterpret_cast<const v8bf*>(qrow);
        qf[1] = *reinterpret_cast<const v8bf*>(qrow + 16);
        qf[2] = *reinterpret_cast<const v8bf*>(qrow + 32);
        qf[3] = *reinterpret_cast<const v8bf*>(qrow + 48);
    }

    const int sr = tid >> 3, sb = tid & 7;

    auto eload = [&](int baseRow, v8bf eb[8]) {
        #pragma unroll
        for (int jc = 0; jc < 2; ++jc)
            #pragma unroll
            for (int ks = 0; ks < 4; ++ks)
                eb[jc * 4 + ks] = *reinterpret_cast<const v8bf*>(
                    Ep + (long)(baseRow + jc * 32 + l31) * 64 + ks * 16 + g2 * 8);
    };

    // T-GEMM: T[l][colBase + j_local] = q[l] . E[rows], j_local via D-layout
    auto tgemm = [&](const v8bf eb[8], int colBase) {
        #pragma unroll
        for (int jc = 0; jc < 2; ++jc) {
            f32x16 tacc;
            #pragma unroll
            for (int r = 0; r < 16; ++r) tacc[r] = 0.f;
            __builtin_amdgcn_s_setprio(1);
            #pragma unroll
            for (int ks = 0; ks < 4; ++ks)
                tacc = MFMA32(eb[jc * 4 + ks], qf[ks], tacc);
            __builtin_amdgcn_s_setprio(0);
            #pragma unroll
            for (int r2 = 0; r2 < 4; ++r2) {
                v4bf w;
                w[0] = (__bf16)tacc[4 * r2 + 0]; w[1] = (__bf16)tacc[4 * r2 + 1];
                w[2] = (__bf16)tacc[4 * r2 + 2]; w[3] = (__bf16)tacc[4 * r2 + 3];
                const int col = colBase + jc * 32 + 8 * r2 + 4 * g2;
                *reinterpret_cast<v4bf*>(Tw + l31 * 130 + col) = w;
            }
        }
    };

    // ---- prologue: stage K/V tile 0; T window [wb0, wb0+128) ----
    {
        const v8bf k0a = *reinterpret_cast<const v8bf*>(kp + (size_t)sr * 64 + sb * 8);
        const v8bf k0b = *reinterpret_cast<const v8bf*>(kp + (size_t)(sr + 32) * 64 + sb * 8);
        const v8bf v0a = *reinterpret_cast<const v8bf*>(vtp + (size_t)sr * 2048 + sb * 8);
        const v8bf v0b = *reinterpret_cast<const v8bf*>(vtp + (size_t)(sr + 32) * 2048 + sb * 8);
        v8bf ebA[8], ebB[8];
        eload(wb0, ebA);
        eload(wb0 + 64, ebB);
        *reinterpret_cast<v8bf*>(&Kl[sr * 64 + ((sb ^ (sr & 7)) << 3)]) = k0a;
        *reinterpret_cast<v8bf*>(&Kl[(sr + 32) * 64 + ((sb ^ (sr & 7)) << 3)]) = k0b;
        *reinterpret_cast<v8bf*>(&Vl[sr * 64 + ((sb ^ (sr & 7)) << 3)]) = v0a;
        *reinterpret_cast<v8bf*>(&Vl[(sr + 32) * 64 + ((sb ^ (sr & 7)) << 3)]) = v0b;
        __syncthreads();
        tgemm(ebA, 0);
        tgemm(ebB, 64);
    }

    f32x16 oacc[2];
    #pragma unroll
    for (int dc = 0; dc < 2; ++dc)
        #pragma unroll
        for (int r = 0; r < 16; ++r) oacc[dc][r] = 0.f;
    float lrow = 0.f;

    for (int t = 0; t < 32; ++t) {
        const int m0 = t * 64;
        const bool lastT = (t == 31);
        const bool needRel = (m0 <= lw0 + 31);
        const bool fullAdd = (m0 + 63 <= lw0);
        const bool needTnext = (m0 + 64 <= lw0 + 31);
        const int lob = 64 * (t & 1);

        // E loads for next window's hi block
        v8bf ebN[8];
        if (needTnext) eload(wb0 + 64 * t + 128, ebN);

        // K/V prefetch for t+1
        v8bf kra, krb, vra, vrb;
        if (!lastT) {
            const int m1 = m0 + 64;
            kra = *reinterpret_cast<const v8bf*>(kp + (size_t)(m1 + sr) * 64 + sb * 8);
            krb = *reinterpret_cast<const v8bf*>(kp + (size_t)(m1 + sr + 32) * 64 + sb * 8);
            vra = *reinterpret_cast<const v8bf*>(vtp + (size_t)sr * 2048 + m1 + sb * 8);
            vrb = *reinterpret_cast<const v8bf*>(vtp + (size_t)(sr + 32) * 2048 + m1 + sb * 8);
        }

        // ---- QK^T (swapped: D[col=l][row=m]) + rel gather + exp + pack, per 32-m chunk
        #pragma unroll
        for (int mc = 0; mc < 2; ++mc) {
            f32x16 sacc;
            #pragma unroll
            for (int r = 0; r < 16; ++r) sacc[r] = 0.f;
            __builtin_amdgcn_s_setprio(1);
            #pragma unroll
            for (int ks = 0; ks < 4; ++ks) {
                const int row = mc * 32 + l31;
                const v8bf kb = *reinterpret_cast<const v8bf*>(
                    &Kl[row * 64 + (((2 * ks + g2) ^ (l31 & 7)) << 3)]);
                sacc = MFMA32(kb, qf[ks], sacc);
            }
            __builtin_amdgcn_s_setprio(0);

            if (needRel) {
                const int cb = 63 - l31 + lob;
                if (fullAdd) {
                    #pragma unroll
                    for (int r2 = 0; r2 < 4; ++r2)
                        #pragma unroll
                        for (int i2 = 0; i2 < 4; ++i2) {
                            const int mtl = mc * 32 + 8 * r2 + 4 * g2 + i2;
                            const int c = (cb + mtl) & 127;
                            sacc[4 * r2 + i2] += (float)Tw[l31 * 130 + c];
                        }
                } else {
                    const int R = lw0 + l31 - m0;      // add iff m_tl <= R
                    #pragma unroll
                    for (int r2 = 0; r2 < 4; ++r2)
                        #pragma unroll
                        for (int i2 = 0; i2 < 4; ++i2) {
                            const int mtl = mc * 32 + 8 * r2 + 4 * g2 + i2;
                            const int c = (cb + mtl) & 127;
                            const float tv = (float)Tw[l31 * 130 + c];
                            sacc[4 * r2 + i2] += (mtl <= R) ? tv : 0.f;
                        }
                }
            }

            // exp2 + row-sum + pack P (bf16) into per-wave LDS
            #pragma unroll
            for (int jj = 0; jj < 4; ++jj) {
                const float p0 = exp2f(sacc[4 * jj + 0]);
                const float p1 = exp2f(sacc[4 * jj + 1]);
                const float p2 = exp2f(sacc[4 * jj + 2]);
                const float p3 = exp2f(sacc[4 * jj + 3]);
                lrow += (p0 + p1) + (p2 + p3);
                v4bf w;
                w[0] = (__bf16)p0; w[1] = (__bf16)p1; w[2] = (__bf16)p2; w[3] = (__bf16)p3;
                *reinterpret_cast<v4bf*>(Pw + l31 * 66 + mc * 32 + 8 * jj + 4 * g2) = w;
            }
        }

        // ---- new-hi T block for t+1 (after gather read the retiring lo cols) ----
        if (needTnext) tgemm(ebN, lob);

        // ---- O += P V  (A = V^T rows d, B = P cols l) ----
        #pragma unroll
        for (int ks = 0; ks < 4; ++ks) {
            const v8bf pa = *reinterpret_cast<const v8bf*>(Pw + l31 * 66 + ks * 16 + g2 * 8);
            __builtin_amdgcn_s_setprio(1);
            #pragma unroll
            for (int dc = 0; dc < 2; ++dc) {
                const int row = dc * 32 + l31;
                const v8bf vb = *reinterpret_cast<const v8bf*>(
                    &Vl[row * 64 + (((2 * ks + g2) ^ (l31 & 7)) << 3)]);
                oacc[dc] = MFMA32(vb, pa, oacc[dc]);
            }
            __builtin_amdgcn_s_setprio(0);
        }

        // ---- single-buffer K/V swap ----
        __syncthreads();
        if (!lastT) {
            *reinterpret_cast<v8bf*>(&Kl[sr * 64 + ((sb ^ (sr & 7)) << 3)]) = kra;
            *reinterpret_cast<v8bf*>(&Kl[(sr + 32) * 64 + ((sb ^ (sr & 7)) << 3)]) = krb;
            *reinterpret_cast<v8bf*>(&Vl[sr * 64 + ((sb ^ (sr & 7)) << 3)]) = vra;
            *reinterpret_cast<v8bf*>(&Vl[(sr + 32) * 64 + ((sb ^ (sr & 7)) << 3)]) = vrb;
        }
        __syncthreads();
    }

    // ---- epilogue: normalize, stage O in LDS (alias Tl), coalesced bf16 store ----
    lrow += __shfl_xor(lrow, 32);
    const float inv = 1.0f / lrow;

    __syncthreads();
    __bf16* Ol = &Tl[0][0];                   // [128][72] bf16 (18.4K <= 32.5K)
    #pragma unroll
    for (int dc = 0; dc < 2; ++dc)
        #pragma unroll
        for (int r2 = 0; r2 < 4; ++r2) {
            v4bf w;
            w[0] = (__bf16)(oacc[dc][4 * r2 + 0] * inv);
            w[1] = (__bf16)(oacc[dc][4 * r2 + 1] * inv);
            w[2] = (__bf16)(oacc[dc][4 * r2 + 2] * inv);
            w[3] = (__bf16)(oacc[dc][4 * r2 + 3] * inv);
            const int d0 = dc * 32 + 8 * r2 + 4 * g2;
            *reinterpret_cast<v4bf*>(Ol + (wid * 32 + l31) * 72 + d0) = w;
        }
    __syncthreads();

    const int b = bh >> 4, h = bh & 15;
    #pragma unroll
    for (int p = 0; p < 4; ++p) {
        const int row = p * 32 + (tid >> 3);
        const v8bf w = *reinterpret_cast<const v8bf*>(Ol + row * 72 + (tid & 7) * 8);
        *reinterpret_cast<v8bf*>(ao + (size_t)(b * 2048 + l0 + row) * 1024 + h * 64 + (tid & 7) * 8) = w;
    }
}

extern "C" void kernel_launch(void* const* d_in, const int* in_sizes, int n_in,
                              void* d_out, int out_size, void* d_ws, size_t ws_size,
                              hipStream_t stream) {
    (void)in_sizes; (void)n_in; (void)out_size; (void)ws_size;
    const float* query = (const float*)d_in[0];
    const float* key   = (const float*)d_in[1];
    const float* value = (const float*)d_in[2];
    const float* Wq    = (const float*)d_in[3];
    const float* bq    = (const float*)d_in[4];
    const float* Wk    = (const float*)d_in[5];
    const float* bk    = (const float*)d_in[6];
    const float* Wv    = (const float*)d_in[7];
    const float* bv    = (const float*)d_in[8];
    const float* Wo    = (const float*)d_in[9];
    const float* bo    = (const float*)d_in[10];
    const float* rel   = (const float*)d_in[11];
    float* out = (float*)d_out;

    __bf16* q_bf  = (__bf16*)d_ws;            // [32][2048][64]   8 MiB (prescaled)
    __bf16* k_bf  = q_bf + 4194304;           //                  8 MiB
    __bf16* vt_bf = k_bf + 4194304;           // [32][64][2048]   8 MiB
    __bf16* Wt4   = vt_bf + 4194304;          // 4x [1024][1024]  8 MiB
    __bf16* E_pad = Wt4 + 4194304;            // [2304][64]       0.28 MiB
    __bf16* aob   = E_pad + 147456;           // [4096][1024]     8 MiB

    const dim3 blk(256);

    cast_rel<<<144, blk, 0, stream>>>(rel, E_pad);
    transpose_cast_w4<<<dim3(16, 16, 4), blk, 0, stream>>>(Wq, Wk, Wv, Wo, Wt4);
    gemm_proj3<<<dim3(16, 32, 3), blk, 0, stream>>>(query, key, value, Wt4,
                                                    bq, bk, bv, q_bf, k_bf, vt_bf);
    attn_mfma<<<dim3(16, 32), blk, 0, stream>>>(q_bf, k_bf, vt_bf,
                                                E_pad + 128 * 64, aob);
    gemm_out<<<dim3(16, 32), blk, 0, stream>>>(aob, Wt4 + 3 * 1048576, bo, out);
}

// Round 10
// 235.080 us; speedup vs baseline: 1.3609x; 1.2798x over previous
//
#include <hip/hip_runtime.h>
#include <hip/hip_bf16.h>

// B=2, L=2048, D=1024, H=16, DH=64, M=2048
// logits[l,m] = (q[l].k[m] + (m<=l ? q[l].E[2047+m-l] : 0)) / 8, E[j]=rel[j+1]
// softmax over all m (no causal mask), out = (attn@v reshaped) @ Wo + bo
// Round 10: r4 structure with ALIGNED strides (T=132, P=72 — r9's 130/66 broke
// 8B/16B LDS alignment), q prescaled, V via direct global A-frags (r7-verified
// addressing), Kl double-buffered -> ONE barrier per m-step.

typedef __bf16 v8bf __attribute__((ext_vector_type(8)));
typedef __bf16 v4bf __attribute__((ext_vector_type(4)));
typedef float f32x4 __attribute__((ext_vector_type(4)));
typedef float f32x16 __attribute__((ext_vector_type(16)));

#define MFMA16(A,B,C) __builtin_amdgcn_mfma_f32_16x16x32_bf16((A),(B),(C),0,0,0)
#define MFMA32(A,B,C) __builtin_amdgcn_mfma_f32_32x32x16_bf16((A),(B),(C),0,0,0)

constexpr float kQScale = 0.1803368801111244f;   // log2(e)/8

// ---------------- rel -> E_pad [2304][64] bf16: rows 128..2175 = rel[1:2049], else 0
__global__ __launch_bounds__(256)
void cast_rel(const float* __restrict__ rel, __bf16* __restrict__ E)
{
    const int i = blockIdx.x * 256 + threadIdx.x;   // 4-elem units, 2304*16 total
    if (i >= 2304 * 16) return;
    const int base = i * 4;
    const int row = base >> 6;
    const int prow = row - 128;
    v4bf o;
    if (prow >= 0 && prow < 2048) {
        const float4 v = *reinterpret_cast<const float4*>(&rel[(size_t)(prow + 1) * 64 + (base & 63)]);
        o[0] = (__bf16)v.x; o[1] = (__bf16)v.y; o[2] = (__bf16)v.z; o[3] = (__bf16)v.w;
    } else {
        o[0] = (__bf16)0.f; o[1] = (__bf16)0.f; o[2] = (__bf16)0.f; o[3] = (__bf16)0.f;
    }
    *reinterpret_cast<v4bf*>(&E[base]) = o;
}

// ---------------- 4x W [1024][1024] fp32 -> Wt [n][k] bf16 (transpose+cast) ----------------
__global__ __launch_bounds__(256)
void transpose_cast_w4(const float* __restrict__ W0, const float* __restrict__ W1,
                       const float* __restrict__ W2, const float* __restrict__ W3,
                       __bf16* __restrict__ Wt4)
{
    __shared__ float tile[64][65];
    const int z = blockIdx.z;
    const float* W = (z == 0) ? W0 : (z == 1) ? W1 : (z == 2) ? W2 : W3;
    __bf16* Wt = Wt4 + (size_t)z * 1048576;
    const int r0 = blockIdx.y * 64, c0 = blockIdx.x * 64;
    const int tr = threadIdx.x >> 4;
    const int tc = (threadIdx.x & 15) * 4;
    #pragma unroll
    for (int p = 0; p < 4; ++p) {
        const int r = tr + p * 16;
        const float4 v = *reinterpret_cast<const float4*>(&W[(size_t)(r0 + r) * 1024 + c0 + tc]);
        tile[r][tc + 0] = v.x; tile[r][tc + 1] = v.y; tile[r][tc + 2] = v.z; tile[r][tc + 3] = v.w;
    }
    __syncthreads();
    #pragma unroll
    for (int p = 0; p < 4; ++p) {
        const int cr = tr + p * 16;
        v4bf o;
        o[0] = (__bf16)tile[tc + 0][cr];
        o[1] = (__bf16)tile[tc + 1][cr];
        o[2] = (__bf16)tile[tc + 2][cr];
        o[3] = (__bf16)tile[tc + 3][cr];
        *reinterpret_cast<v4bf*>(&Wt[(size_t)(c0 + cr) * 1024 + r0 + tc]) = o;
    }
}

// ---------------- bf16 MFMA GEMM body: C = A[4096x1024] @ Wt^T + bias ----------------
// mode 0: fp32 flat out; mode 1: bf16 heads [bh][l][64] (scaled by oscale);
// mode 2: bf16 [bh][dh][2048]
template <bool ABF16>
__device__ __forceinline__
void gemm_body(const float* __restrict__ Af, const __bf16* __restrict__ Ab,
               const __bf16* __restrict__ Wt, const float* __restrict__ bias,
               float* __restrict__ Cf, __bf16* __restrict__ Cb, int mode,
               float oscale, int bx, int by)
{
    __shared__ __bf16 As[2][128 * 64];
    __shared__ __bf16 Ws[2][64 * 64];
    const int tid = threadIdx.x;
    const int wid = tid >> 6, lane = tid & 63, g = lane >> 4, li = lane & 15;
    const int r0 = by * 128, c0 = bx * 64;
    const int wr = wid >> 1, wc = wid & 1;
    const int sr = tid >> 3, sb = tid & 7;

    f32x4 acc[4][2];
    #pragma unroll
    for (int a = 0; a < 4; ++a)
        #pragma unroll
        for (int b2 = 0; b2 < 2; ++b2) acc[a][b2] = f32x4{0.f, 0.f, 0.f, 0.f};

    v8bf areg[4], wreg[2];

    auto loadA = [&](int p, int kt) -> v8bf {
        if constexpr (ABF16) {
            return *reinterpret_cast<const v8bf*>(&Ab[(size_t)(r0 + sr + 32 * p) * 1024 + kt + sb * 8]);
        } else {
            const float* ar = &Af[(size_t)(r0 + sr + 32 * p) * 1024 + kt + sb * 8];
            const float4 f0 = *reinterpret_cast<const float4*>(ar);
            const float4 f1 = *reinterpret_cast<const float4*>(ar + 4);
            v8bf a8;
            a8[0] = (__bf16)f0.x; a8[1] = (__bf16)f0.y; a8[2] = (__bf16)f0.z; a8[3] = (__bf16)f0.w;
            a8[4] = (__bf16)f1.x; a8[5] = (__bf16)f1.y; a8[6] = (__bf16)f1.z; a8[7] = (__bf16)f1.w;
            return a8;
        }
    };

    #pragma unroll
    for (int p = 0; p < 4; ++p) areg[p] = loadA(p, 0);
    #pragma unroll
    for (int p = 0; p < 2; ++p)
        wreg[p] = *reinterpret_cast<const v8bf*>(&Wt[(size_t)(c0 + sr + 32 * p) * 1024 + sb * 8]);
    #pragma unroll
    for (int p = 0; p < 4; ++p) {
        const int row = sr + 32 * p;
        *reinterpret_cast<v8bf*>(&As[0][row * 64 + ((sb ^ (row & 7)) << 3)]) = areg[p];
    }
    #pragma unroll
    for (int p = 0; p < 2; ++p) {
        const int row = sr + 32 * p;
        *reinterpret_cast<v8bf*>(&Ws[0][row * 64 + ((sb ^ (row & 7)) << 3)]) = wreg[p];
    }
    __syncthreads();

    for (int ki = 0; ki < 16; ++ki) {
        const int cur = ki & 1;
        if (ki < 15) {
            const int kt = (ki + 1) * 64;
            #pragma unroll
            for (int p = 0; p < 4; ++p) areg[p] = loadA(p, kt);
            #pragma unroll
            for (int p = 0; p < 2; ++p)
                wreg[p] = *reinterpret_cast<const v8bf*>(&Wt[(size_t)(c0 + sr + 32 * p) * 1024 + kt + sb * 8]);
        }
        #pragma unroll
        for (int ks = 0; ks < 2; ++ks) {
            v8bf af[4], bfr[2];
            #pragma unroll
            for (int fm = 0; fm < 4; ++fm) {
                const int row = wr * 64 + fm * 16 + li;
                af[fm] = *reinterpret_cast<const v8bf*>(
                    &As[cur][row * 64 + (((ks * 4 + g) ^ (row & 7)) << 3)]);
            }
            #pragma unroll
            for (int fn = 0; fn < 2; ++fn) {
                const int row = wc * 32 + fn * 16 + li;
                bfr[fn] = *reinterpret_cast<const v8bf*>(
                    &Ws[cur][row * 64 + (((ks * 4 + g) ^ (row & 7)) << 3)]);
            }
            __builtin_amdgcn_s_setprio(1);
            #pragma unroll
            for (int fm = 0; fm < 4; ++fm)
                #pragma unroll
                for (int fn = 0; fn < 2; ++fn)
                    acc[fm][fn] = MFMA16(af[fm], bfr[fn], acc[fm][fn]);
            __builtin_amdgcn_s_setprio(0);
        }
        if (ki < 15) {
            const int nxt = cur ^ 1;
            #pragma unroll
            for (int p = 0; p < 4; ++p) {
                const int row = sr + 32 * p;
                *reinterpret_cast<v8bf*>(&As[nxt][row * 64 + ((sb ^ (row & 7)) << 3)]) = areg[p];
            }
            #pragma unroll
            for (int p = 0; p < 2; ++p) {
                const int row = sr + 32 * p;
                *reinterpret_cast<v8bf*>(&Ws[nxt][row * 64 + ((sb ^ (row & 7)) << 3)]) = wreg[p];
            }
        }
        __syncthreads();
    }

    #pragma unroll
    for (int fn = 0; fn < 2; ++fn) {
        const int col = c0 + wc * 32 + fn * 16 + li;
        const float bb = bias[col];
        #pragma unroll
        for (int fm = 0; fm < 4; ++fm) {
            if (mode == 2) {
                const int row = r0 + wr * 64 + fm * 16 + 4 * g;
                const int b = row >> 11, l = row & 2047;
                const int h = col >> 6, dh = col & 63;
                v4bf pk;
                #pragma unroll
                for (int reg = 0; reg < 4; ++reg)
                    pk[reg] = (__bf16)(acc[fm][fn][reg] + bb);
                *reinterpret_cast<v4bf*>(&Cb[((size_t)((b * 16 + h) * 64 + dh)) * 2048 + l]) = pk;
            } else {
                #pragma unroll
                for (int reg = 0; reg < 4; ++reg) {
                    const int row = r0 + wr * 64 + fm * 16 + 4 * g + reg;
                    const float val = acc[fm][fn][reg] + bb;
                    if (mode == 0) {
                        Cf[(size_t)row * 1024 + col] = val;
                    } else {
                        const int b = row >> 11, l = row & 2047, h = col >> 6, dh = col & 63;
                        Cb[((size_t)(b * 16 + h) * 2048 + l) * 64 + dh] = (__bf16)(val * oscale);
                    }
                }
            }
        }
    }
}

__global__ __launch_bounds__(256)
void gemm_proj3(const float* __restrict__ Aq, const float* __restrict__ Ak,
                const float* __restrict__ Av, const __bf16* __restrict__ Wt4,
                const float* __restrict__ bq, const float* __restrict__ bk,
                const float* __restrict__ bv, __bf16* __restrict__ qo,
                __bf16* __restrict__ ko, __bf16* __restrict__ vto)
{
    const int z = blockIdx.z;
    const float* A = (z == 0) ? Aq : (z == 1) ? Ak : Av;
    const __bf16* Wt = Wt4 + (size_t)z * 1048576;
    const float* bias = (z == 0) ? bq : (z == 1) ? bk : bv;
    __bf16* Cb = (z == 0) ? qo : (z == 1) ? ko : vto;
    const float osc = (z == 0) ? kQScale : 1.0f;
    gemm_body<false>(A, nullptr, Wt, bias, nullptr, Cb, (z == 2) ? 2 : 1, osc,
                     blockIdx.x, blockIdx.y);
}

__global__ __launch_bounds__(256)
void gemm_out(const __bf16* __restrict__ A, const __bf16* __restrict__ Wt,
              const float* __restrict__ bias, float* __restrict__ C)
{
    gemm_body<true>(nullptr, A, Wt, bias, C, nullptr, 0, 1.0f, blockIdx.x, blockIdx.y);
}

// ---------------- fused attention: 32x32 MFMA, swapped operands ----------------
// q,k: [32][2048][64] bf16 (q prescaled); vt: [32][64][2048] bf16;
// Ep: padded E (rows -128..2175 valid); ao: [4096][1024] bf16.
// Block = 256 thr = 4 waves x 32 q-rows; 32 m-steps of 64.
// K staged in double-buffered LDS (ONE barrier/step); V direct global A-frags
// (r7-verified); per-wave T ring (stride 132) + P strip (stride 72), aligned.
__global__ __launch_bounds__(256, 2)
void attn_mfma(const __bf16* __restrict__ q, const __bf16* __restrict__ k,
               const __bf16* __restrict__ vt, const __bf16* __restrict__ Ep,
               __bf16* __restrict__ ao)
{
    __shared__ __bf16 Kl[2][64 * 64];     // dbuf [m][d], 16B-block XOR swizzle (16K)
    __shared__ __bf16 Tl[4][32 * 132];    // per-wave T window [32 rows][128+4] (33K)
    __shared__ __bf16 Pl[4][32 * 72];     // per-wave P [32 rows][64+8] (18K)

    const int tid = threadIdx.x;
    const int wid = tid >> 6;
    const int lane = tid & 63;
    const int l31 = lane & 31;
    const int g2 = lane >> 5;

    // XCD-aware remap: all 16 q-tiles of a bh land on one XCD (K/V L2 locality)
    const int flat = blockIdx.y * 16 + blockIdx.x;
    const int jj_ = flat >> 3;
    const int bh = (flat & 7) * 4 + (jj_ >> 4);
    const int qt = jj_ & 15;

    const int l0 = qt * 128;
    const int lw0 = l0 + wid * 32;            // wave's first q-row
    const size_t hbase = (size_t)bh * (2048 * 64);
    const __bf16* qp = q + hbase;
    const __bf16* kp = k + hbase;
    const __bf16* vtp = vt + hbase;           // [64][2048]
    const int wb0 = 1984 - lw0;               // per-wave e-window base at t=0

    __bf16* Tw = &Tl[wid][0];
    __bf16* Pw = &Pl[wid][0];

    // Q B-fragments (col = l lane-local), prescaled by log2e/8 at projection
    v8bf qf[4];
    {
        const __bf16* qrow = qp + (size_t)(lw0 + l31) * 64 + g2 * 8;
        qf[0] = *reinterpret_cast<const v8bf*>(qrow);
        qf[1] = *reinterpret_cast<const v8bf*>(qrow + 16);
        qf[2] = *reinterpret_cast<const v8bf*>(qrow + 32);
        qf[3] = *reinterpret_cast<const v8bf*>(qrow + 48);
    }

    const int sr = tid >> 3, sb = tid & 7;

    auto eload = [&](int baseRow, v8bf eb[8]) {
        #pragma unroll
        for (int jc = 0; jc < 2; ++jc)
            #pragma unroll
            for (int ks = 0; ks < 4; ++ks)
                eb[jc * 4 + ks] = *reinterpret_cast<const v8bf*>(
                    Ep + (long)(baseRow + jc * 32 + l31) * 64 + ks * 16 + g2 * 8);
    };

    // T-GEMM: T[l][colBase + j_local] = q[l] . E[rows], j_local via D-layout
    auto tgemm = [&](const v8bf eb[8], int colBase) {
        #pragma unroll
        for (int jc = 0; jc < 2; ++jc) {
            f32x16 tacc;
            #pragma unroll
            for (int r = 0; r < 16; ++r) tacc[r] = 0.f;
            __builtin_amdgcn_s_setprio(1);
            #pragma unroll
            for (int ks = 0; ks < 4; ++ks)
                tacc = MFMA32(eb[jc * 4 + ks], qf[ks], tacc);
            __builtin_amdgcn_s_setprio(0);
            #pragma unroll
            for (int r2 = 0; r2 < 4; ++r2) {
                v4bf w;
                w[0] = (__bf16)tacc[4 * r2 + 0]; w[1] = (__bf16)tacc[4 * r2 + 1];
                w[2] = (__bf16)tacc[4 * r2 + 2]; w[3] = (__bf16)tacc[4 * r2 + 3];
                const int col = colBase + jc * 32 + 8 * r2 + 4 * g2;
                *reinterpret_cast<v4bf*>(Tw + l31 * 132 + col) = w;
            }
        }
    };

    // ---- prologue: stage K tile 0 into Kl[0]; T window [wb0, wb0+128) ----
    {
        const v8bf k0a = *reinterpret_cast<const v8bf*>(kp + (size_t)sr * 64 + sb * 8);
        const v8bf k0b = *reinterpret_cast<const v8bf*>(kp + (size_t)(sr + 32) * 64 + sb * 8);
        v8bf ebA[8], ebB[8];
        eload(wb0, ebA);
        eload(wb0 + 64, ebB);
        *reinterpret_cast<v8bf*>(&Kl[0][sr * 64 + ((sb ^ (sr & 7)) << 3)]) = k0a;
        *reinterpret_cast<v8bf*>(&Kl[0][(sr + 32) * 64 + ((sb ^ (sr & 7)) << 3)]) = k0b;
        __syncthreads();
        tgemm(ebA, 0);
        tgemm(ebB, 64);
    }

    f32x16 oacc[2];
    #pragma unroll
    for (int dc = 0; dc < 2; ++dc)
        #pragma unroll
        for (int r = 0; r < 16; ++r) oacc[dc][r] = 0.f;
    float lrow = 0.f;

    for (int t = 0; t < 32; ++t) {
        const int m0 = t * 64;
        const int cur = t & 1, nxt = cur ^ 1;
        const bool lastT = (t == 31);
        const bool needRel = (m0 <= lw0 + 31);
        const bool fullAdd = (m0 + 63 <= lw0);
        const bool needTnext = (m0 + 64 <= lw0 + 31);
        const int lob = 64 * (t & 1);

        // E loads for next window's hi block
        v8bf ebN[8];
        if (needTnext) eload(wb0 + 64 * t + 128, ebN);

        // K prefetch for t+1 (written to Kl[nxt] after PV)
        v8bf kra, krb;
        if (!lastT) {
            const int m1 = m0 + 64;
            kra = *reinterpret_cast<const v8bf*>(kp + (size_t)(m1 + sr) * 64 + sb * 8);
            krb = *reinterpret_cast<const v8bf*>(kp + (size_t)(m1 + sr + 32) * 64 + sb * 8);
        }

        // V A-frags direct from global (r7-verified addressing; consumed at PV)
        v8bf vb0[4], vb1[4];
        #pragma unroll
        for (int ks = 0; ks < 4; ++ks) {
            vb0[ks] = *reinterpret_cast<const v8bf*>(
                vtp + (size_t)(l31) * 2048 + m0 + ks * 16 + g2 * 8);
            vb1[ks] = *reinterpret_cast<const v8bf*>(
                vtp + (size_t)(32 + l31) * 2048 + m0 + ks * 16 + g2 * 8);
        }

        // ---- QK^T (swapped: D[col=l][row=m]) + rel gather + exp + pack, per 32-m chunk
        #pragma unroll
        for (int mc = 0; mc < 2; ++mc) {
            f32x16 sacc;
            #pragma unroll
            for (int r = 0; r < 16; ++r) sacc[r] = 0.f;
            __builtin_amdgcn_s_setprio(1);
            #pragma unroll
            for (int ks = 0; ks < 4; ++ks) {
                const int row = mc * 32 + l31;
                const v8bf kb = *reinterpret_cast<const v8bf*>(
                    &Kl[cur][row * 64 + (((2 * ks + g2) ^ (l31 & 7)) << 3)]);
                sacc = MFMA32(kb, qf[ks], sacc);
            }
            __builtin_amdgcn_s_setprio(0);

            if (needRel) {
                const int cb = 63 - l31 + lob;
                if (fullAdd) {
                    #pragma unroll
                    for (int r2 = 0; r2 < 4; ++r2)
                        #pragma unroll
                        for (int i2 = 0; i2 < 4; ++i2) {
                            const int mtl = mc * 32 + 8 * r2 + 4 * g2 + i2;
                            const int c = (cb + mtl) & 127;
                            sacc[4 * r2 + i2] += (float)Tw[l31 * 132 + c];
                        }
                } else {
                    const int R = lw0 + l31 - m0;      // add iff m_tl <= R
                    #pragma unroll
                    for (int r2 = 0; r2 < 4; ++r2)
                        #pragma unroll
                        for (int i2 = 0; i2 < 4; ++i2) {
                            const int mtl = mc * 32 + 8 * r2 + 4 * g2 + i2;
                            const int c = (cb + mtl) & 127;
                            const float tv = (float)Tw[l31 * 132 + c];
                            sacc[4 * r2 + i2] += (mtl <= R) ? tv : 0.f;
                        }
                }
            }

            // exp2 + row-sum + pack P (bf16) into per-wave LDS (stride 72, aligned)
            #pragma unroll
            for (int jj = 0; jj < 4; ++jj) {
                const float p0 = exp2f(sacc[4 * jj + 0]);
                const float p1 = exp2f(sacc[4 * jj + 1]);
                const float p2 = exp2f(sacc[4 * jj + 2]);
                const float p3 = exp2f(sacc[4 * jj + 3]);
                lrow += (p0 + p1) + (p2 + p3);
                v4bf w;
                w[0] = (__bf16)p0; w[1] = (__bf16)p1; w[2] = (__bf16)p2; w[3] = (__bf16)p3;
                *reinterpret_cast<v4bf*>(Pw + l31 * 72 + mc * 32 + 8 * jj + 4 * g2) = w;
            }
        }

        // ---- new-hi T block for t+1 (after gather read the retiring lo cols) ----
        if (needTnext) tgemm(ebN, lob);

        // ---- O += P V (A = V^T direct-global rows d, B = P from Pw) ----
        #pragma unroll
        for (int ks = 0; ks < 4; ++ks) {
            const v8bf pa = *reinterpret_cast<const v8bf*>(Pw + l31 * 72 + ks * 16 + g2 * 8);
            __builtin_amdgcn_s_setprio(1);
            oacc[0] = MFMA32(vb0[ks], pa, oacc[0]);
            oacc[1] = MFMA32(vb1[ks], pa, oacc[1]);
            __builtin_amdgcn_s_setprio(0);
        }

        // ---- write next K tile to the other buffer; ONE barrier per step ----
        if (!lastT) {
            *reinterpret_cast<v8bf*>(&Kl[nxt][sr * 64 + ((sb ^ (sr & 7)) << 3)]) = kra;
            *reinterpret_cast<v8bf*>(&Kl[nxt][(sr + 32) * 64 + ((sb ^ (sr & 7)) << 3)]) = krb;
        }
        __syncthreads();
    }

    // ---- epilogue: normalize, stage O in LDS (alias Tl), coalesced bf16 store ----
    lrow += __shfl_xor(lrow, 32);
    const float inv = 1.0f / lrow;

    __syncthreads();
    __bf16* Ol = &Tl[0][0];                   // [128][72] bf16 (18.4K <= 33K)
    #pragma unroll
    for (int dc = 0; dc < 2; ++dc)
        #pragma unroll
        for (int r2 = 0; r2 < 4; ++r2) {
            v4bf w;
            w[0] = (__bf16)(oacc[dc][4 * r2 + 0] * inv);
            w[1] = (__bf16)(oacc[dc][4 * r2 + 1] * inv);
            w[2] = (__bf16)(oacc[dc][4 * r2 + 2] * inv);
            w[3] = (__bf16)(oacc[dc][4 * r2 + 3] * inv);
            const int d0 = dc * 32 + 8 * r2 + 4 * g2;
            *reinterpret_cast<v4bf*>(Ol + (wid * 32 + l31) * 72 + d0) = w;
        }
    __syncthreads();

    const int b = bh >> 4, h = bh & 15;
    #pragma unroll
    for (int p = 0; p < 4; ++p) {
        const int row = p * 32 + (tid >> 3);
        const v8bf w = *reinterpret_cast<const v8bf*>(Ol + row * 72 + (tid & 7) * 8);
        *reinterpret_cast<v8bf*>(ao + (size_t)(b * 2048 + l0 + row) * 1024 + h * 64 + (tid & 7) * 8) = w;
    }
}

extern "C" void kernel_launch(void* const* d_in, const int* in_sizes, int n_in,
                              void* d_out, int out_size, void* d_ws, size_t ws_size,
                              hipStream_t stream) {
    (void)in_sizes; (void)n_in; (void)out_size; (void)ws_size;
    const float* query = (const float*)d_in[0];
    const float* key   = (const float*)d_in[1];
    const float* value = (const float*)d_in[2];
    const float* Wq    = (const float*)d_in[3];
    const float* bq    = (const float*)d_in[4];
    const float* Wk    = (const float*)d_in[5];
    const float* bk    = (const float*)d_in[6];
    const float* Wv    = (const float*)d_in[7];
    const float* bv    = (const float*)d_in[8];
    const float* Wo    = (const float*)d_in[9];
    const float* bo    = (const float*)d_in[10];
    const float* rel   = (const float*)d_in[11];
    float* out = (float*)d_out;

    __bf16* q_bf  = (__bf16*)d_ws;            // [32][2048][64]   8 MiB (prescaled)
    __bf16* k_bf  = q_bf + 4194304;           //                  8 MiB
    __bf16* vt_bf = k_bf + 4194304;           // [32][64][2048]   8 MiB
    __bf16* Wt4   = vt_bf + 4194304;          // 4x [1024][1024]  8 MiB
    __bf16* E_pad = Wt4 + 4194304;            // [2304][64]       0.28 MiB
    __bf16* aob   = E_pad + 147456;           // [4096][1024]     8 MiB

    const dim3 blk(256);

    cast_rel<<<144, blk, 0, stream>>>(rel, E_pad);
    transpose_cast_w4<<<dim3(16, 16, 4), blk, 0, stream>>>(Wq, Wk, Wv, Wo, Wt4);
    gemm_proj3<<<dim3(16, 32, 3), blk, 0, stream>>>(query, key, value, Wt4,
                                                    bq, bk, bv, q_bf, k_bf, vt_bf);
    attn_mfma<<<dim3(16, 32), blk, 0, stream>>>(q_bf, k_bf, vt_bf,
                                                E_pad + 128 * 64, aob);
    gemm_out<<<dim3(16, 32), blk, 0, stream>>>(aob, Wt4 + 3 * 1048576, bo, out);
}

// Round 11
// 205.224 us; speedup vs baseline: 1.5589x; 1.1455x over previous
//
#include <hip/hip_runtime.h>
#include <hip/hip_bf16.h>

// B=2, L=2048, D=1024, H=16, DH=64, M=2048
// logits[l,m] = (q[l].k[m] + (m<=l ? q[l].E[2047+m-l] : 0)) / 8, E[j]=rel[j+1]
// softmax over all m (no causal mask), out = (attn@v reshaped) @ Wo + bo
// Round 11: attention restored to the round-4-verified kernel (122us) with
// q-prescale only; GEMMs upgraded to 128x128 tiles (2 MFMA per ds_read_b128).

typedef __bf16 v8bf __attribute__((ext_vector_type(8)));
typedef __bf16 v4bf __attribute__((ext_vector_type(4)));
typedef float f32x4 __attribute__((ext_vector_type(4)));
typedef float f32x16 __attribute__((ext_vector_type(16)));

#define MFMA16(A,B,C) __builtin_amdgcn_mfma_f32_16x16x32_bf16((A),(B),(C),0,0,0)
#define MFMA32(A,B,C) __builtin_amdgcn_mfma_f32_32x32x16_bf16((A),(B),(C),0,0,0)

constexpr float kQScale = 0.1803368801111244f;   // log2(e)/8

// ---------------- rel -> E_pad [2304][64] bf16: rows 128..2175 = rel[1:2049], else 0
__global__ __launch_bounds__(256)
void cast_rel(const float* __restrict__ rel, __bf16* __restrict__ E)
{
    const int i = blockIdx.x * 256 + threadIdx.x;   // 4-elem units, 2304*16 total
    if (i >= 2304 * 16) return;
    const int base = i * 4;
    const int row = base >> 6;
    const int prow = row - 128;
    v4bf o;
    if (prow >= 0 && prow < 2048) {
        const float4 v = *reinterpret_cast<const float4*>(&rel[(size_t)(prow + 1) * 64 + (base & 63)]);
        o[0] = (__bf16)v.x; o[1] = (__bf16)v.y; o[2] = (__bf16)v.z; o[3] = (__bf16)v.w;
    } else {
        o[0] = (__bf16)0.f; o[1] = (__bf16)0.f; o[2] = (__bf16)0.f; o[3] = (__bf16)0.f;
    }
    *reinterpret_cast<v4bf*>(&E[base]) = o;
}

// ---------------- 4x W [1024][1024] fp32 -> Wt [n][k] bf16 (transpose+cast) ----------------
__global__ __launch_bounds__(256)
void transpose_cast_w4(const float* __restrict__ W0, const float* __restrict__ W1,
                       const float* __restrict__ W2, const float* __restrict__ W3,
                       __bf16* __restrict__ Wt4)
{
    __shared__ float tile[64][65];
    const int z = blockIdx.z;
    const float* W = (z == 0) ? W0 : (z == 1) ? W1 : (z == 2) ? W2 : W3;
    __bf16* Wt = Wt4 + (size_t)z * 1048576;
    const int r0 = blockIdx.y * 64, c0 = blockIdx.x * 64;
    const int tr = threadIdx.x >> 4;
    const int tc = (threadIdx.x & 15) * 4;
    #pragma unroll
    for (int p = 0; p < 4; ++p) {
        const int r = tr + p * 16;
        const float4 v = *reinterpret_cast<const float4*>(&W[(size_t)(r0 + r) * 1024 + c0 + tc]);
        tile[r][tc + 0] = v.x; tile[r][tc + 1] = v.y; tile[r][tc + 2] = v.z; tile[r][tc + 3] = v.w;
    }
    __syncthreads();
    #pragma unroll
    for (int p = 0; p < 4; ++p) {
        const int cr = tr + p * 16;
        v4bf o;
        o[0] = (__bf16)tile[tc + 0][cr];
        o[1] = (__bf16)tile[tc + 1][cr];
        o[2] = (__bf16)tile[tc + 2][cr];
        o[3] = (__bf16)tile[tc + 3][cr];
        *reinterpret_cast<v4bf*>(&Wt[(size_t)(c0 + cr) * 1024 + r0 + tc]) = o;
    }
}

// ---------------- bf16 MFMA GEMM body: C = A[4096x1024] @ Wt^T + bias, 128x128 tile ----
// mode 0: fp32 flat out; mode 1: bf16 heads [bh][l][64] (scaled by oscale);
// mode 2: bf16 [bh][dh][2048]
template <bool ABF16>
__device__ __forceinline__
void gemm_body(const float* __restrict__ Af, const __bf16* __restrict__ Ab,
               const __bf16* __restrict__ Wt, const float* __restrict__ bias,
               float* __restrict__ Cf, __bf16* __restrict__ Cb, int mode,
               float oscale, int bx, int by)
{
    __shared__ __bf16 As[2][128 * 64];
    __shared__ __bf16 Ws[2][128 * 64];
    const int tid = threadIdx.x;
    const int wid = tid >> 6, lane = tid & 63, g = lane >> 4, li = lane & 15;
    const int r0 = by * 128, c0 = bx * 128;
    const int wr = wid >> 1, wc = wid & 1;        // wave quadrant (64x64)
    const int sr = tid >> 3, sb = tid & 7;

    f32x4 acc[4][4];
    #pragma unroll
    for (int a = 0; a < 4; ++a)
        #pragma unroll
        for (int b2 = 0; b2 < 4; ++b2) acc[a][b2] = f32x4{0.f, 0.f, 0.f, 0.f};

    v8bf areg[4], wreg[4];

    auto loadA = [&](int p, int kt) -> v8bf {
        if constexpr (ABF16) {
            return *reinterpret_cast<const v8bf*>(&Ab[(size_t)(r0 + sr + 32 * p) * 1024 + kt + sb * 8]);
        } else {
            const float* ar = &Af[(size_t)(r0 + sr + 32 * p) * 1024 + kt + sb * 8];
            const float4 f0 = *reinterpret_cast<const float4*>(ar);
            const float4 f1 = *reinterpret_cast<const float4*>(ar + 4);
            v8bf a8;
            a8[0] = (__bf16)f0.x; a8[1] = (__bf16)f0.y; a8[2] = (__bf16)f0.z; a8[3] = (__bf16)f0.w;
            a8[4] = (__bf16)f1.x; a8[5] = (__bf16)f1.y; a8[6] = (__bf16)f1.z; a8[7] = (__bf16)f1.w;
            return a8;
        }
    };
    auto loadW = [&](int p, int kt) -> v8bf {
        return *reinterpret_cast<const v8bf*>(&Wt[(size_t)(c0 + sr + 32 * p) * 1024 + kt + sb * 8]);
    };

    #pragma unroll
    for (int p = 0; p < 4; ++p) { areg[p] = loadA(p, 0); wreg[p] = loadW(p, 0); }
    #pragma unroll
    for (int p = 0; p < 4; ++p) {
        const int row = sr + 32 * p;
        *reinterpret_cast<v8bf*>(&As[0][row * 64 + ((sb ^ (row & 7)) << 3)]) = areg[p];
        *reinterpret_cast<v8bf*>(&Ws[0][row * 64 + ((sb ^ (row & 7)) << 3)]) = wreg[p];
    }
    __syncthreads();

    for (int ki = 0; ki < 16; ++ki) {
        const int cur = ki & 1;
        if (ki < 15) {
            const int kt = (ki + 1) * 64;
            #pragma unroll
            for (int p = 0; p < 4; ++p) { areg[p] = loadA(p, kt); wreg[p] = loadW(p, kt); }
        }
        #pragma unroll
        for (int ks = 0; ks < 2; ++ks) {
            v8bf af[4], bfr[4];
            #pragma unroll
            for (int fm = 0; fm < 4; ++fm) {
                const int row = wr * 64 + fm * 16 + li;
                af[fm] = *reinterpret_cast<const v8bf*>(
                    &As[cur][row * 64 + (((ks * 4 + g) ^ (row & 7)) << 3)]);
            }
            #pragma unroll
            for (int fn = 0; fn < 4; ++fn) {
                const int row = wc * 64 + fn * 16 + li;
                bfr[fn] = *reinterpret_cast<const v8bf*>(
                    &Ws[cur][row * 64 + (((ks * 4 + g) ^ (row & 7)) << 3)]);
            }
            __builtin_amdgcn_s_setprio(1);
            #pragma unroll
            for (int fm = 0; fm < 4; ++fm)
                #pragma unroll
                for (int fn = 0; fn < 4; ++fn)
                    acc[fm][fn] = MFMA16(af[fm], bfr[fn], acc[fm][fn]);
            __builtin_amdgcn_s_setprio(0);
        }
        if (ki < 15) {
            const int nxt = cur ^ 1;
            #pragma unroll
            for (int p = 0; p < 4; ++p) {
                const int row = sr + 32 * p;
                *reinterpret_cast<v8bf*>(&As[nxt][row * 64 + ((sb ^ (row & 7)) << 3)]) = areg[p];
                *reinterpret_cast<v8bf*>(&Ws[nxt][row * 64 + ((sb ^ (row & 7)) << 3)]) = wreg[p];
            }
        }
        __syncthreads();
    }

    #pragma unroll
    for (int fn = 0; fn < 4; ++fn) {
        const int col = c0 + wc * 64 + fn * 16 + li;
        const float bb = bias[col];
        #pragma unroll
        for (int fm = 0; fm < 4; ++fm) {
            if (mode == 2) {
                const int row = r0 + wr * 64 + fm * 16 + 4 * g;
                const int b = row >> 11, l = row & 2047;
                const int h = col >> 6, dh = col & 63;
                v4bf pk;
                #pragma unroll
                for (int reg = 0; reg < 4; ++reg)
                    pk[reg] = (__bf16)(acc[fm][fn][reg] + bb);
                *reinterpret_cast<v4bf*>(&Cb[((size_t)((b * 16 + h) * 64 + dh)) * 2048 + l]) = pk;
            } else {
                #pragma unroll
                for (int reg = 0; reg < 4; ++reg) {
                    const int row = r0 + wr * 64 + fm * 16 + 4 * g + reg;
                    const float val = acc[fm][fn][reg] + bb;
                    if (mode == 0) {
                        Cf[(size_t)row * 1024 + col] = val;
                    } else {
                        const int b = row >> 11, l = row & 2047, h = col >> 6, dh = col & 63;
                        Cb[((size_t)(b * 16 + h) * 2048 + l) * 64 + dh] = (__bf16)(val * oscale);
                    }
                }
            }
        }
    }
}

__global__ __launch_bounds__(256)
void gemm_proj3(const float* __restrict__ Aq, const float* __restrict__ Ak,
                const float* __restrict__ Av, const __bf16* __restrict__ Wt4,
                const float* __restrict__ bq, const float* __restrict__ bk,
                const float* __restrict__ bv, __bf16* __restrict__ qo,
                __bf16* __restrict__ ko, __bf16* __restrict__ vto)
{
    const int z = blockIdx.z;
    const float* A = (z == 0) ? Aq : (z == 1) ? Ak : Av;
    const __bf16* Wt = Wt4 + (size_t)z * 1048576;
    const float* bias = (z == 0) ? bq : (z == 1) ? bk : bv;
    __bf16* Cb = (z == 0) ? qo : (z == 1) ? ko : vto;
    const float osc = (z == 0) ? kQScale : 1.0f;
    gemm_body<false>(A, nullptr, Wt, bias, nullptr, Cb, (z == 2) ? 2 : 1, osc,
                     blockIdx.x, blockIdx.y);
}

__global__ __launch_bounds__(256)
void gemm_out(const __bf16* __restrict__ A, const __bf16* __restrict__ Wt,
              const float* __restrict__ bias, float* __restrict__ C)
{
    gemm_body<true>(nullptr, A, Wt, bias, C, nullptr, 0, 1.0f, blockIdx.x, blockIdx.y);
}

// ---------------- fused attention: round-4-verified kernel (q prescaled) ----------------
// q,k: [32][2048][64] bf16 (q prescaled); vt: [32][64][2048] bf16;
// Ep: padded E (rows -128..2175 valid); ao: [4096][1024] bf16.
// Block = 256 thr = 4 waves x 32 q-rows; 32 m-steps of 64; K/V staged in shared
// single-buffered LDS (2 barriers/step, reg prefetch); per-wave T ring (132) and
// P strip (72), both 16B-aligned strides.
__global__ __launch_bounds__(256, 2)
void attn_mfma(const __bf16* __restrict__ q, const __bf16* __restrict__ k,
               const __bf16* __restrict__ vt, const __bf16* __restrict__ Ep,
               __bf16* __restrict__ ao)
{
    __shared__ __bf16 Kl[64 * 64];        // [m][d], 16B-block XOR swizzle (8K)
    __shared__ __bf16 Vl[64 * 64];        // [d][m], swizzled (8K)
    __shared__ __bf16 Tl[4][32 * 132];    // per-wave T window [32 rows][128+4] (33K)
    __shared__ __bf16 Pl[4][32 * 72];     // per-wave P [32 rows][64+8] (18K)

    const int tid = threadIdx.x;
    const int wid = tid >> 6;
    const int lane = tid & 63;
    const int l31 = lane & 31;
    const int g2 = lane >> 5;

    // XCD-aware remap: all 16 q-tiles of a bh land on one XCD (K/V L2 locality)
    const int flat = blockIdx.y * 16 + blockIdx.x;
    const int jj_ = flat >> 3;
    const int bh = (flat & 7) * 4 + (jj_ >> 4);
    const int qt = jj_ & 15;

    const int l0 = qt * 128;
    const int lw0 = l0 + wid * 32;            // wave's first q-row
    const size_t hbase = (size_t)bh * (2048 * 64);
    const __bf16* qp = q + hbase;
    const __bf16* kp = k + hbase;
    const __bf16* vtp = vt + hbase;           // [64][2048]
    const int wb0 = 1984 - l0 - 32 * wid;     // per-wave e-window base at t=0

    __bf16* Tw = &Tl[wid][0];
    __bf16* Pw = &Pl[wid][0];

    // Q B-fragments (col = l lane-local), prescaled by log2e/8 at projection
    v8bf qf[4];
    {
        const __bf16* qrow = qp + (size_t)(lw0 + l31) * 64 + g2 * 8;
        qf[0] = *reinterpret_cast<const v8bf*>(qrow);
        qf[1] = *reinterpret_cast<const v8bf*>(qrow + 16);
        qf[2] = *reinterpret_cast<const v8bf*>(qrow + 32);
        qf[3] = *reinterpret_cast<const v8bf*>(qrow + 48);
    }

    const int sr = tid >> 3, sb = tid & 7;

    auto eload = [&](int baseRow, v8bf eb[8]) {
        #pragma unroll
        for (int jc = 0; jc < 2; ++jc)
            #pragma unroll
            for (int ks = 0; ks < 4; ++ks)
                eb[jc * 4 + ks] = *reinterpret_cast<const v8bf*>(
                    Ep + (long)(baseRow + jc * 32 + l31) * 64 + ks * 16 + g2 * 8);
    };

    // T-GEMM: T[l][colBase + j_local] = q[l] . E[rows], j_local via D-layout
    auto tgemm = [&](const v8bf eb[8], int colBase) {
        #pragma unroll
        for (int jc = 0; jc < 2; ++jc) {
            f32x16 tacc;
            #pragma unroll
            for (int r = 0; r < 16; ++r) tacc[r] = 0.f;
            __builtin_amdgcn_s_setprio(1);
            #pragma unroll
            for (int ks = 0; ks < 4; ++ks)
                tacc = MFMA32(eb[jc * 4 + ks], qf[ks], tacc);
            __builtin_amdgcn_s_setprio(0);
            #pragma unroll
            for (int r2 = 0; r2 < 4; ++r2) {
                v4bf w;
                w[0] = (__bf16)tacc[4 * r2 + 0]; w[1] = (__bf16)tacc[4 * r2 + 1];
                w[2] = (__bf16)tacc[4 * r2 + 2]; w[3] = (__bf16)tacc[4 * r2 + 3];
                const int col = colBase + jc * 32 + 8 * r2 + 4 * g2;
                *reinterpret_cast<v4bf*>(Tw + l31 * 132 + col) = w;
            }
        }
    };

    // ---- prologue: stage K/V tile 0; T window [wb0, wb0+128) ----
    {
        const v8bf k0a = *reinterpret_cast<const v8bf*>(kp + (size_t)sr * 64 + sb * 8);
        const v8bf k0b = *reinterpret_cast<const v8bf*>(kp + (size_t)(sr + 32) * 64 + sb * 8);
        const v8bf v0a = *reinterpret_cast<const v8bf*>(vtp + (size_t)sr * 2048 + sb * 8);
        const v8bf v0b = *reinterpret_cast<const v8bf*>(vtp + (size_t)(sr + 32) * 2048 + sb * 8);
        v8bf ebA[8], ebB[8];
        eload(wb0, ebA);
        eload(wb0 + 64, ebB);
        *reinterpret_cast<v8bf*>(&Kl[sr * 64 + ((sb ^ (sr & 7)) << 3)]) = k0a;
        *reinterpret_cast<v8bf*>(&Kl[(sr + 32) * 64 + ((sb ^ (sr & 7)) << 3)]) = k0b;
        *reinterpret_cast<v8bf*>(&Vl[sr * 64 + ((sb ^ (sr & 7)) << 3)]) = v0a;
        *reinterpret_cast<v8bf*>(&Vl[(sr + 32) * 64 + ((sb ^ (sr & 7)) << 3)]) = v0b;
        __syncthreads();
        tgemm(ebA, 0);
        tgemm(ebB, 64);
    }

    f32x16 oacc[2];
    #pragma unroll
    for (int dc = 0; dc < 2; ++dc)
        #pragma unroll
        for (int r = 0; r < 16; ++r) oacc[dc][r] = 0.f;
    float lrow = 0.f;

    for (int t = 0; t < 32; ++t) {
        const int m0 = t * 64;
        const bool lastT = (t == 31);
        const bool needRel = (m0 <= lw0 + 31);
        const bool fullAdd = (m0 + 63 <= lw0);
        const bool needTnext = (m0 + 64 <= lw0 + 31);
        const int lob = 64 * (t & 1);

        // E loads for next window's hi block
        v8bf ebN[8];
        if (needTnext) eload(wb0 + 64 * t + 128, ebN);

        // K/V prefetch for t+1
        v8bf kra, krb, vra, vrb;
        if (!lastT) {
            const int m1 = m0 + 64;
            kra = *reinterpret_cast<const v8bf*>(kp + (size_t)(m1 + sr) * 64 + sb * 8);
            krb = *reinterpret_cast<const v8bf*>(kp + (size_t)(m1 + sr + 32) * 64 + sb * 8);
            vra = *reinterpret_cast<const v8bf*>(vtp + (size_t)sr * 2048 + m1 + sb * 8);
            vrb = *reinterpret_cast<const v8bf*>(vtp + (size_t)(sr + 32) * 2048 + m1 + sb * 8);
        }

        // ---- QK^T (swapped: D[col=l][row=m]) + rel gather + exp + pack, per 32-m chunk
        #pragma unroll
        for (int mc = 0; mc < 2; ++mc) {
            f32x16 sacc;
            #pragma unroll
            for (int r = 0; r < 16; ++r) sacc[r] = 0.f;
            __builtin_amdgcn_s_setprio(1);
            #pragma unroll
            for (int ks = 0; ks < 4; ++ks) {
                const int row = mc * 32 + l31;
                const v8bf kb = *reinterpret_cast<const v8bf*>(
                    &Kl[row * 64 + (((2 * ks + g2) ^ (l31 & 7)) << 3)]);
                sacc = MFMA32(kb, qf[ks], sacc);
            }
            __builtin_amdgcn_s_setprio(0);

            if (needRel) {
                const int cb = 63 - l31 + lob;
                if (fullAdd) {
                    #pragma unroll
                    for (int r2 = 0; r2 < 4; ++r2)
                        #pragma unroll
                        for (int i2 = 0; i2 < 4; ++i2) {
                            const int mtl = mc * 32 + 8 * r2 + 4 * g2 + i2;
                            const int c = (cb + mtl) & 127;
                            sacc[4 * r2 + i2] += (float)Tw[l31 * 132 + c];
                        }
                } else {
                    const int R = lw0 + l31 - m0;      // add iff m_tl <= R
                    #pragma unroll
                    for (int r2 = 0; r2 < 4; ++r2)
                        #pragma unroll
                        for (int i2 = 0; i2 < 4; ++i2) {
                            const int mtl = mc * 32 + 8 * r2 + 4 * g2 + i2;
                            const int c = (cb + mtl) & 127;
                            const float tv = (float)Tw[l31 * 132 + c];
                            sacc[4 * r2 + i2] += (mtl <= R) ? tv : 0.f;
                        }
                }
            }

            // exp2 + row-sum + pack P (bf16) into per-wave LDS
            #pragma unroll
            for (int jj = 0; jj < 4; ++jj) {
                const float p0 = exp2f(sacc[4 * jj + 0]);
                const float p1 = exp2f(sacc[4 * jj + 1]);
                const float p2 = exp2f(sacc[4 * jj + 2]);
                const float p3 = exp2f(sacc[4 * jj + 3]);
                lrow += (p0 + p1) + (p2 + p3);
                v4bf w;
                w[0] = (__bf16)p0; w[1] = (__bf16)p1; w[2] = (__bf16)p2; w[3] = (__bf16)p3;
                *reinterpret_cast<v4bf*>(Pw + l31 * 72 + mc * 32 + 8 * jj + 4 * g2) = w;
            }
        }

        // ---- new-hi T block for t+1 (after gather read the retiring lo cols) ----
        if (needTnext) tgemm(ebN, lob);

        // ---- O += P V  (A = V^T rows d, B = P cols l) ----
        #pragma unroll
        for (int ks = 0; ks < 4; ++ks) {
            const v8bf pa = *reinterpret_cast<const v8bf*>(Pw + l31 * 72 + ks * 16 + g2 * 8);
            __builtin_amdgcn_s_setprio(1);
            #pragma unroll
            for (int dc = 0; dc < 2; ++dc) {
                const int row = dc * 32 + l31;
                const v8bf vb = *reinterpret_cast<const v8bf*>(
                    &Vl[row * 64 + (((2 * ks + g2) ^ (l31 & 7)) << 3)]);
                oacc[dc] = MFMA32(vb, pa, oacc[dc]);
            }
            __builtin_amdgcn_s_setprio(0);
        }

        // ---- single-buffer K/V swap ----
        __syncthreads();
        if (!lastT) {
            *reinterpret_cast<v8bf*>(&Kl[sr * 64 + ((sb ^ (sr & 7)) << 3)]) = kra;
            *reinterpret_cast<v8bf*>(&Kl[(sr + 32) * 64 + ((sb ^ (sr & 7)) << 3)]) = krb;
            *reinterpret_cast<v8bf*>(&Vl[sr * 64 + ((sb ^ (sr & 7)) << 3)]) = vra;
            *reinterpret_cast<v8bf*>(&Vl[(sr + 32) * 64 + ((sb ^ (sr & 7)) << 3)]) = vrb;
        }
        __syncthreads();
    }

    // ---- epilogue: normalize, stage O in LDS (alias Tl), coalesced bf16 store ----
    lrow += __shfl_xor(lrow, 32);
    const float inv = 1.0f / lrow;

    __syncthreads();
    __bf16* Ol = &Tl[0][0];                   // [128][72] bf16 (18.4K <= 33K)
    #pragma unroll
    for (int dc = 0; dc < 2; ++dc)
        #pragma unroll
        for (int r2 = 0; r2 < 4; ++r2) {
            v4bf w;
            w[0] = (__bf16)(oacc[dc][4 * r2 + 0] * inv);
            w[1] = (__bf16)(oacc[dc][4 * r2 + 1] * inv);
            w[2] = (__bf16)(oacc[dc][4 * r2 + 2] * inv);
            w[3] = (__bf16)(oacc[dc][4 * r2 + 3] * inv);
            const int d0 = dc * 32 + 8 * r2 + 4 * g2;
            *reinterpret_cast<v4bf*>(Ol + (wid * 32 + l31) * 72 + d0) = w;
        }
    __syncthreads();

    const int b = bh >> 4, h = bh & 15;
    #pragma unroll
    for (int p = 0; p < 4; ++p) {
        const int row = p * 32 + (tid >> 3);
        const v8bf w = *reinterpret_cast<const v8bf*>(Ol + row * 72 + (tid & 7) * 8);
        *reinterpret_cast<v8bf*>(ao + (size_t)(b * 2048 + l0 + row) * 1024 + h * 64 + (tid & 7) * 8) = w;
    }
}

extern "C" void kernel_launch(void* const* d_in, const int* in_sizes, int n_in,
                              void* d_out, int out_size, void* d_ws, size_t ws_size,
                              hipStream_t stream) {
    (void)in_sizes; (void)n_in; (void)out_size; (void)ws_size;
    const float* query = (const float*)d_in[0];
    const float* key   = (const float*)d_in[1];
    const float* value = (const float*)d_in[2];
    const float* Wq    = (const float*)d_in[3];
    const float* bq    = (const float*)d_in[4];
    const float* Wk    = (const float*)d_in[5];
    const float* bk    = (const float*)d_in[6];
    const float* Wv    = (const float*)d_in[7];
    const float* bv    = (const float*)d_in[8];
    const float* Wo    = (const float*)d_in[9];
    const float* bo    = (const float*)d_in[10];
    const float* rel   = (const float*)d_in[11];
    float* out = (float*)d_out;

    __bf16* q_bf  = (__bf16*)d_ws;            // [32][2048][64]   8 MiB (prescaled)
    __bf16* k_bf  = q_bf + 4194304;           //                  8 MiB
    __bf16* vt_bf = k_bf + 4194304;           // [32][64][2048]   8 MiB
    __bf16* Wt4   = vt_bf + 4194304;          // 4x [1024][1024]  8 MiB
    __bf16* E_pad = Wt4 + 4194304;            // [2304][64]       0.28 MiB
    __bf16* aob   = E_pad + 147456;           // [4096][1024]     8 MiB

    const dim3 blk(256);

    cast_rel<<<144, blk, 0, stream>>>(rel, E_pad);
    transpose_cast_w4<<<dim3(16, 16, 4), blk, 0, stream>>>(Wq, Wk, Wv, Wo, Wt4);
    gemm_proj3<<<dim3(8, 32, 3), blk, 0, stream>>>(query, key, value, Wt4,
                                                   bq, bk, bv, q_bf, k_bf, vt_bf);
    attn_mfma<<<dim3(16, 32), blk, 0, stream>>>(q_bf, k_bf, vt_bf,
                                                E_pad + 128 * 64, aob);
    gemm_out<<<dim3(8, 32), blk, 0, stream>>>(aob, Wt4 + 3 * 1048576, bo, out);
}

// Round 12
// 187.045 us; speedup vs baseline: 1.7104x; 1.0972x over previous
//
#include <hip/hip_runtime.h>
#include <hip/hip_bf16.h>

// B=2, L=2048, D=1024, H=16, DH=64, M=2048
// logits[l,m] = (q[l].k[m] + (m<=l ? q[l].E[2047+m-l] : 0)) / 8, E[j]=rel[j+1]
// softmax over all m (no causal mask), out = (attn@v reshaped) @ Wo + bo
// Round 12: r11 + (a) XOR-swizzled T ring (stride 128) and P strip (stride 64)
// -> conflict-free at natural strides, one extra XOR per access;
// (b) XCD-aware block remap in both GEMMs for A-panel L2 reuse.

typedef __bf16 v8bf __attribute__((ext_vector_type(8)));
typedef __bf16 v4bf __attribute__((ext_vector_type(4)));
typedef float f32x4 __attribute__((ext_vector_type(4)));
typedef float f32x16 __attribute__((ext_vector_type(16)));

#define MFMA16(A,B,C) __builtin_amdgcn_mfma_f32_16x16x32_bf16((A),(B),(C),0,0,0)
#define MFMA32(A,B,C) __builtin_amdgcn_mfma_f32_32x32x16_bf16((A),(B),(C),0,0,0)

constexpr float kQScale = 0.1803368801111244f;   // log2(e)/8

// ---------------- rel -> E_pad [2304][64] bf16: rows 128..2175 = rel[1:2049], else 0
__global__ __launch_bounds__(256)
void cast_rel(const float* __restrict__ rel, __bf16* __restrict__ E)
{
    const int i = blockIdx.x * 256 + threadIdx.x;   // 4-elem units, 2304*16 total
    if (i >= 2304 * 16) return;
    const int base = i * 4;
    const int row = base >> 6;
    const int prow = row - 128;
    v4bf o;
    if (prow >= 0 && prow < 2048) {
        const float4 v = *reinterpret_cast<const float4*>(&rel[(size_t)(prow + 1) * 64 + (base & 63)]);
        o[0] = (__bf16)v.x; o[1] = (__bf16)v.y; o[2] = (__bf16)v.z; o[3] = (__bf16)v.w;
    } else {
        o[0] = (__bf16)0.f; o[1] = (__bf16)0.f; o[2] = (__bf16)0.f; o[3] = (__bf16)0.f;
    }
    *reinterpret_cast<v4bf*>(&E[base]) = o;
}

// ---------------- 4x W [1024][1024] fp32 -> Wt [n][k] bf16 (transpose+cast) ----------------
__global__ __launch_bounds__(256)
void transpose_cast_w4(const float* __restrict__ W0, const float* __restrict__ W1,
                       const float* __restrict__ W2, const float* __restrict__ W3,
                       __bf16* __restrict__ Wt4)
{
    __shared__ float tile[64][65];
    const int z = blockIdx.z;
    const float* W = (z == 0) ? W0 : (z == 1) ? W1 : (z == 2) ? W2 : W3;
    __bf16* Wt = Wt4 + (size_t)z * 1048576;
    const int r0 = blockIdx.y * 64, c0 = blockIdx.x * 64;
    const int tr = threadIdx.x >> 4;
    const int tc = (threadIdx.x & 15) * 4;
    #pragma unroll
    for (int p = 0; p < 4; ++p) {
        const int r = tr + p * 16;
        const float4 v = *reinterpret_cast<const float4*>(&W[(size_t)(r0 + r) * 1024 + c0 + tc]);
        tile[r][tc + 0] = v.x; tile[r][tc + 1] = v.y; tile[r][tc + 2] = v.z; tile[r][tc + 3] = v.w;
    }
    __syncthreads();
    #pragma unroll
    for (int p = 0; p < 4; ++p) {
        const int cr = tr + p * 16;
        v4bf o;
        o[0] = (__bf16)tile[tc + 0][cr];
        o[1] = (__bf16)tile[tc + 1][cr];
        o[2] = (__bf16)tile[tc + 2][cr];
        o[3] = (__bf16)tile[tc + 3][cr];
        *reinterpret_cast<v4bf*>(&Wt[(size_t)(c0 + cr) * 1024 + r0 + tc]) = o;
    }
}

// ---------------- bf16 MFMA GEMM body: C = A[4096x1024] @ Wt^T + bias, 128x128 tile ----
// mode 0: fp32 flat out; mode 1: bf16 heads [bh][l][64] (scaled by oscale);
// mode 2: bf16 [bh][dh][2048]
template <bool ABF16>
__device__ __forceinline__
void gemm_body(const float* __restrict__ Af, const __bf16* __restrict__ Ab,
               const __bf16* __restrict__ Wt, const float* __restrict__ bias,
               float* __restrict__ Cf, __bf16* __restrict__ Cb, int mode,
               float oscale, int bx, int by)
{
    __shared__ __bf16 As[2][128 * 64];
    __shared__ __bf16 Ws[2][128 * 64];
    const int tid = threadIdx.x;
    const int wid = tid >> 6, lane = tid & 63, g = lane >> 4, li = lane & 15;
    const int r0 = by * 128, c0 = bx * 128;
    const int wr = wid >> 1, wc = wid & 1;        // wave quadrant (64x64)
    const int sr = tid >> 3, sb = tid & 7;

    f32x4 acc[4][4];
    #pragma unroll
    for (int a = 0; a < 4; ++a)
        #pragma unroll
        for (int b2 = 0; b2 < 4; ++b2) acc[a][b2] = f32x4{0.f, 0.f, 0.f, 0.f};

    v8bf areg[4], wreg[4];

    auto loadA = [&](int p, int kt) -> v8bf {
        if constexpr (ABF16) {
            return *reinterpret_cast<const v8bf*>(&Ab[(size_t)(r0 + sr + 32 * p) * 1024 + kt + sb * 8]);
        } else {
            const float* ar = &Af[(size_t)(r0 + sr + 32 * p) * 1024 + kt + sb * 8];
            const float4 f0 = *reinterpret_cast<const float4*>(ar);
            const float4 f1 = *reinterpret_cast<const float4*>(ar + 4);
            v8bf a8;
            a8[0] = (__bf16)f0.x; a8[1] = (__bf16)f0.y; a8[2] = (__bf16)f0.z; a8[3] = (__bf16)f0.w;
            a8[4] = (__bf16)f1.x; a8[5] = (__bf16)f1.y; a8[6] = (__bf16)f1.z; a8[7] = (__bf16)f1.w;
            return a8;
        }
    };
    auto loadW = [&](int p, int kt) -> v8bf {
        return *reinterpret_cast<const v8bf*>(&Wt[(size_t)(c0 + sr + 32 * p) * 1024 + kt + sb * 8]);
    };

    #pragma unroll
    for (int p = 0; p < 4; ++p) { areg[p] = loadA(p, 0); wreg[p] = loadW(p, 0); }
    #pragma unroll
    for (int p = 0; p < 4; ++p) {
        const int row = sr + 32 * p;
        *reinterpret_cast<v8bf*>(&As[0][row * 64 + ((sb ^ (row & 7)) << 3)]) = areg[p];
        *reinterpret_cast<v8bf*>(&Ws[0][row * 64 + ((sb ^ (row & 7)) << 3)]) = wreg[p];
    }
    __syncthreads();

    for (int ki = 0; ki < 16; ++ki) {
        const int cur = ki & 1;
        if (ki < 15) {
            const int kt = (ki + 1) * 64;
            #pragma unroll
            for (int p = 0; p < 4; ++p) { areg[p] = loadA(p, kt); wreg[p] = loadW(p, kt); }
        }
        #pragma unroll
        for (int ks = 0; ks < 2; ++ks) {
            v8bf af[4], bfr[4];
            #pragma unroll
            for (int fm = 0; fm < 4; ++fm) {
                const int row = wr * 64 + fm * 16 + li;
                af[fm] = *reinterpret_cast<const v8bf*>(
                    &As[cur][row * 64 + (((ks * 4 + g) ^ (row & 7)) << 3)]);
            }
            #pragma unroll
            for (int fn = 0; fn < 4; ++fn) {
                const int row = wc * 64 + fn * 16 + li;
                bfr[fn] = *reinterpret_cast<const v8bf*>(
                    &Ws[cur][row * 64 + (((ks * 4 + g) ^ (row & 7)) << 3)]);
            }
            __builtin_amdgcn_s_setprio(1);
            #pragma unroll
            for (int fm = 0; fm < 4; ++fm)
                #pragma unroll
                for (int fn = 0; fn < 4; ++fn)
                    acc[fm][fn] = MFMA16(af[fm], bfr[fn], acc[fm][fn]);
            __builtin_amdgcn_s_setprio(0);
        }
        if (ki < 15) {
            const int nxt = cur ^ 1;
            #pragma unroll
            for (int p = 0; p < 4; ++p) {
                const int row = sr + 32 * p;
                *reinterpret_cast<v8bf*>(&As[nxt][row * 64 + ((sb ^ (row & 7)) << 3)]) = areg[p];
                *reinterpret_cast<v8bf*>(&Ws[nxt][row * 64 + ((sb ^ (row & 7)) << 3)]) = wreg[p];
            }
        }
        __syncthreads();
    }

    #pragma unroll
    for (int fn = 0; fn < 4; ++fn) {
        const int col = c0 + wc * 64 + fn * 16 + li;
        const float bb = bias[col];
        #pragma unroll
        for (int fm = 0; fm < 4; ++fm) {
            if (mode == 2) {
                const int row = r0 + wr * 64 + fm * 16 + 4 * g;
                const int b = row >> 11, l = row & 2047;
                const int h = col >> 6, dh = col & 63;
                v4bf pk;
                #pragma unroll
                for (int reg = 0; reg < 4; ++reg)
                    pk[reg] = (__bf16)(acc[fm][fn][reg] + bb);
                *reinterpret_cast<v4bf*>(&Cb[((size_t)((b * 16 + h) * 64 + dh)) * 2048 + l]) = pk;
            } else {
                #pragma unroll
                for (int reg = 0; reg < 4; ++reg) {
                    const int row = r0 + wr * 64 + fm * 16 + 4 * g + reg;
                    const float val = acc[fm][fn][reg] + bb;
                    if (mode == 0) {
                        Cf[(size_t)row * 1024 + col] = val;
                    } else {
                        const int b = row >> 11, l = row & 2047, h = col >> 6, dh = col & 63;
                        Cb[((size_t)(b * 16 + h) * 2048 + l) * 64 + dh] = (__bf16)(val * oscale);
                    }
                }
            }
        }
    }
}

// XCD remap for (8 x-tiles, 32 y-panels): each XCD gets 4 y-panels x 8 x-tiles
// so the A row-panel is fetched into one XCD's L2 once.
__device__ __forceinline__ void xcd_remap_gemm(int& bx, int& by)
{
    const int flat = by * 8 + bx;          // 0..255
    const int xcd = flat & 7;
    const int idx = flat >> 3;             // 0..31
    by = xcd * 4 + (idx & 3);
    bx = idx >> 2;
}

__global__ __launch_bounds__(256)
void gemm_proj3(const float* __restrict__ Aq, const float* __restrict__ Ak,
                const float* __restrict__ Av, const __bf16* __restrict__ Wt4,
                const float* __restrict__ bq, const float* __restrict__ bk,
                const float* __restrict__ bv, __bf16* __restrict__ qo,
                __bf16* __restrict__ ko, __bf16* __restrict__ vto)
{
    const int z = blockIdx.z;
    const float* A = (z == 0) ? Aq : (z == 1) ? Ak : Av;
    const __bf16* Wt = Wt4 + (size_t)z * 1048576;
    const float* bias = (z == 0) ? bq : (z == 1) ? bk : bv;
    __bf16* Cb = (z == 0) ? qo : (z == 1) ? ko : vto;
    const float osc = (z == 0) ? kQScale : 1.0f;
    int bx = blockIdx.x, by = blockIdx.y;
    xcd_remap_gemm(bx, by);
    gemm_body<false>(A, nullptr, Wt, bias, nullptr, Cb, (z == 2) ? 2 : 1, osc, bx, by);
}

__global__ __launch_bounds__(256)
void gemm_out(const __bf16* __restrict__ A, const __bf16* __restrict__ Wt,
              const float* __restrict__ bias, float* __restrict__ C)
{
    int bx = blockIdx.x, by = blockIdx.y;
    xcd_remap_gemm(bx, by);
    gemm_body<true>(nullptr, A, Wt, bias, C, nullptr, 0, 1.0f, bx, by);
}

// ---------------- fused attention (r4 structure, XOR-swizzled T/P) ----------------
// q,k: [32][2048][64] bf16 (q prescaled); vt: [32][64][2048] bf16;
// Ep: padded E (rows -128..2175 valid); ao: [4096][1024] bf16.
// Block = 256 thr = 4 waves x 32 q-rows; 32 m-steps of 64; K/V staged in shared
// single-buffered LDS (2 barriers/step); per-wave T ring [32][128] and P strip
// [32][64], both XOR-block-swizzled: phys = base + (col ^ ((l31&7)<<3)).
__global__ __launch_bounds__(256, 2)
void attn_mfma(const __bf16* __restrict__ q, const __bf16* __restrict__ k,
               const __bf16* __restrict__ vt, const __bf16* __restrict__ Ep,
               __bf16* __restrict__ ao)
{
    __shared__ __bf16 Kl[64 * 64];        // [m][d], 16B-block XOR swizzle (8K)
    __shared__ __bf16 Vl[64 * 64];        // [d][m], swizzled (8K)
    __shared__ __bf16 Tl[4][32 * 128];    // per-wave T ring, XOR-swizzled (32K)
    __shared__ __bf16 Pl[4][32 * 64];     // per-wave P, XOR-swizzled (16K)

    const int tid = threadIdx.x;
    const int wid = tid >> 6;
    const int lane = tid & 63;
    const int l31 = lane & 31;
    const int g2 = lane >> 5;
    const int xsh = (l31 & 7) << 3;       // XOR pattern (bits 3-5)

    // XCD-aware remap: all 16 q-tiles of a bh land on one XCD (K/V L2 locality)
    const int flat = blockIdx.y * 16 + blockIdx.x;
    const int jj_ = flat >> 3;
    const int bh = (flat & 7) * 4 + (jj_ >> 4);
    const int qt = jj_ & 15;

    const int l0 = qt * 128;
    const int lw0 = l0 + wid * 32;            // wave's first q-row
    const size_t hbase = (size_t)bh * (2048 * 64);
    const __bf16* qp = q + hbase;
    const __bf16* kp = k + hbase;
    const __bf16* vtp = vt + hbase;           // [64][2048]
    const int wb0 = 1984 - l0 - 32 * wid;     // per-wave e-window base at t=0

    __bf16* Tw = &Tl[wid][0];
    __bf16* Pw = &Pl[wid][0];

    // Q B-fragments (col = l lane-local), prescaled by log2e/8 at projection
    v8bf qf[4];
    {
        const __bf16* qrow = qp + (size_t)(lw0 + l31) * 64 + g2 * 8;
        qf[0] = *reinterpret_cast<const v8bf*>(qrow);
        qf[1] = *reinterpret_cast<const v8bf*>(qrow + 16);
        qf[2] = *reinterpret_cast<const v8bf*>(qrow + 32);
        qf[3] = *reinterpret_cast<const v8bf*>(qrow + 48);
    }

    const int sr = tid >> 3, sb = tid & 7;

    auto eload = [&](int baseRow, v8bf eb[8]) {
        #pragma unroll
        for (int jc = 0; jc < 2; ++jc)
            #pragma unroll
            for (int ks = 0; ks < 4; ++ks)
                eb[jc * 4 + ks] = *reinterpret_cast<const v8bf*>(
                    Ep + (long)(baseRow + jc * 32 + l31) * 64 + ks * 16 + g2 * 8);
    };

    // T-GEMM: T[l][colBase + j_local] = q[l] . E[rows]; store XOR-swizzled
    auto tgemm = [&](const v8bf eb[8], int colBase) {
        #pragma unroll
        for (int jc = 0; jc < 2; ++jc) {
            f32x16 tacc;
            #pragma unroll
            for (int r = 0; r < 16; ++r) tacc[r] = 0.f;
            __builtin_amdgcn_s_setprio(1);
            #pragma unroll
            for (int ks = 0; ks < 4; ++ks)
                tacc = MFMA32(eb[jc * 4 + ks], qf[ks], tacc);
            __builtin_amdgcn_s_setprio(0);
            #pragma unroll
            for (int r2 = 0; r2 < 4; ++r2) {
                v4bf w;
                w[0] = (__bf16)tacc[4 * r2 + 0]; w[1] = (__bf16)tacc[4 * r2 + 1];
                w[2] = (__bf16)tacc[4 * r2 + 2]; w[3] = (__bf16)tacc[4 * r2 + 3];
                const int col = colBase + jc * 32 + 8 * r2 + 4 * g2;
                *reinterpret_cast<v4bf*>(Tw + l31 * 128 + (col ^ xsh)) = w;
            }
        }
    };

    // ---- prologue: stage K/V tile 0; T window [wb0, wb0+128) ----
    {
        const v8bf k0a = *reinterpret_cast<const v8bf*>(kp + (size_t)sr * 64 + sb * 8);
        const v8bf k0b = *reinterpret_cast<const v8bf*>(kp + (size_t)(sr + 32) * 64 + sb * 8);
        const v8bf v0a = *reinterpret_cast<const v8bf*>(vtp + (size_t)sr * 2048 + sb * 8);
        const v8bf v0b = *reinterpret_cast<const v8bf*>(vtp + (size_t)(sr + 32) * 2048 + sb * 8);
        v8bf ebA[8], ebB[8];
        eload(wb0, ebA);
        eload(wb0 + 64, ebB);
        *reinterpret_cast<v8bf*>(&Kl[sr * 64 + ((sb ^ (sr & 7)) << 3)]) = k0a;
        *reinterpret_cast<v8bf*>(&Kl[(sr + 32) * 64 + ((sb ^ (sr & 7)) << 3)]) = k0b;
        *reinterpret_cast<v8bf*>(&Vl[sr * 64 + ((sb ^ (sr & 7)) << 3)]) = v0a;
        *reinterpret_cast<v8bf*>(&Vl[(sr + 32) * 64 + ((sb ^ (sr & 7)) << 3)]) = v0b;
        __syncthreads();
        tgemm(ebA, 0);
        tgemm(ebB, 64);
    }

    f32x16 oacc[2];
    #pragma unroll
    for (int dc = 0; dc < 2; ++dc)
        #pragma unroll
        for (int r = 0; r < 16; ++r) oacc[dc][r] = 0.f;
    float lrow = 0.f;

    for (int t = 0; t < 32; ++t) {
        const int m0 = t * 64;
        const bool lastT = (t == 31);
        const bool needRel = (m0 <= lw0 + 31);
        const bool fullAdd = (m0 + 63 <= lw0);
        const bool needTnext = (m0 + 64 <= lw0 + 31);
        const int lob = 64 * (t & 1);

        // E loads for next window's hi block
        v8bf ebN[8];
        if (needTnext) eload(wb0 + 64 * t + 128, ebN);

        // K/V prefetch for t+1
        v8bf kra, krb, vra, vrb;
        if (!lastT) {
            const int m1 = m0 + 64;
            kra = *reinterpret_cast<const v8bf*>(kp + (size_t)(m1 + sr) * 64 + sb * 8);
            krb = *reinterpret_cast<const v8bf*>(kp + (size_t)(m1 + sr + 32) * 64 + sb * 8);
            vra = *reinterpret_cast<const v8bf*>(vtp + (size_t)sr * 2048 + m1 + sb * 8);
            vrb = *reinterpret_cast<const v8bf*>(vtp + (size_t)(sr + 32) * 2048 + m1 + sb * 8);
        }

        // ---- QK^T (swapped: D[col=l][row=m]) + rel gather + exp + pack, per 32-m chunk
        #pragma unroll
        for (int mc = 0; mc < 2; ++mc) {
            f32x16 sacc;
            #pragma unroll
            for (int r = 0; r < 16; ++r) sacc[r] = 0.f;
            __builtin_amdgcn_s_setprio(1);
            #pragma unroll
            for (int ks = 0; ks < 4; ++ks) {
                const int row = mc * 32 + l31;
                const v8bf kb = *reinterpret_cast<const v8bf*>(
                    &Kl[row * 64 + (((2 * ks + g2) ^ (l31 & 7)) << 3)]);
                sacc = MFMA32(kb, qf[ks], sacc);
            }
            __builtin_amdgcn_s_setprio(0);

            if (needRel) {
                const int cb = 63 - l31 + lob;
                if (fullAdd) {
                    #pragma unroll
                    for (int r2 = 0; r2 < 4; ++r2)
                        #pragma unroll
                        for (int i2 = 0; i2 < 4; ++i2) {
                            const int mtl = mc * 32 + 8 * r2 + 4 * g2 + i2;
                            const int c = (cb + mtl) & 127;
                            sacc[4 * r2 + i2] += (float)Tw[l31 * 128 + (c ^ xsh)];
                        }
                } else {
                    const int R = lw0 + l31 - m0;      // add iff m_tl <= R
                    #pragma unroll
                    for (int r2 = 0; r2 < 4; ++r2)
                        #pragma unroll
                        for (int i2 = 0; i2 < 4; ++i2) {
                            const int mtl = mc * 32 + 8 * r2 + 4 * g2 + i2;
                            const int c = (cb + mtl) & 127;
                            const float tv = (float)Tw[l31 * 128 + (c ^ xsh)];
                            sacc[4 * r2 + i2] += (mtl <= R) ? tv : 0.f;
                        }
                }
            }

            // exp2 + row-sum + pack P (bf16) into per-wave LDS (XOR-swizzled)
            #pragma unroll
            for (int jj = 0; jj < 4; ++jj) {
                const float p0 = exp2f(sacc[4 * jj + 0]);
                const float p1 = exp2f(sacc[4 * jj + 1]);
                const float p2 = exp2f(sacc[4 * jj + 2]);
                const float p3 = exp2f(sacc[4 * jj + 3]);
                lrow += (p0 + p1) + (p2 + p3);
                v4bf w;
                w[0] = (__bf16)p0; w[1] = (__bf16)p1; w[2] = (__bf16)p2; w[3] = (__bf16)p3;
                const int col = mc * 32 + 8 * jj + 4 * g2;
                *reinterpret_cast<v4bf*>(Pw + l31 * 64 + (col ^ xsh)) = w;
            }
        }

        // ---- new-hi T block for t+1 (after gather read the retiring lo cols) ----
        if (needTnext) tgemm(ebN, lob);

        // ---- O += P V  (A = V^T rows d, B = P cols l) ----
        #pragma unroll
        for (int ks = 0; ks < 4; ++ks) {
            const v8bf pa = *reinterpret_cast<const v8bf*>(
                Pw + l31 * 64 + ((ks * 16 + g2 * 8) ^ xsh));
            __builtin_amdgcn_s_setprio(1);
            #pragma unroll
            for (int dc = 0; dc < 2; ++dc) {
                const int row = dc * 32 + l31;
                const v8bf vb = *reinterpret_cast<const v8bf*>(
                    &Vl[row * 64 + (((2 * ks + g2) ^ (l31 & 7)) << 3)]);
                oacc[dc] = MFMA32(vb, pa, oacc[dc]);
            }
            __builtin_amdgcn_s_setprio(0);
        }

        // ---- single-buffer K/V swap ----
        __syncthreads();
        if (!lastT) {
            *reinterpret_cast<v8bf*>(&Kl[sr * 64 + ((sb ^ (sr & 7)) << 3)]) = kra;
            *reinterpret_cast<v8bf*>(&Kl[(sr + 32) * 64 + ((sb ^ (sr & 7)) << 3)]) = krb;
            *reinterpret_cast<v8bf*>(&Vl[sr * 64 + ((sb ^ (sr & 7)) << 3)]) = vra;
            *reinterpret_cast<v8bf*>(&Vl[(sr + 32) * 64 + ((sb ^ (sr & 7)) << 3)]) = vrb;
        }
        __syncthreads();
    }

    // ---- epilogue: normalize, stage O in LDS (alias Tl), coalesced bf16 store ----
    lrow += __shfl_xor(lrow, 32);
    const float inv = 1.0f / lrow;

    __syncthreads();
    __bf16* Ol = &Tl[0][0];                   // [128][72] bf16 (18.4K <= 32K)
    #pragma unroll
    for (int dc = 0; dc < 2; ++dc)
        #pragma unroll
        for (int r2 = 0; r2 < 4; ++r2) {
            v4bf w;
            w[0] = (__bf16)(oacc[dc][4 * r2 + 0] * inv);
            w[1] = (__bf16)(oacc[dc][4 * r2 + 1] * inv);
            w[2] = (__bf16)(oacc[dc][4 * r2 + 2] * inv);
            w[3] = (__bf16)(oacc[dc][4 * r2 + 3] * inv);
            const int d0 = dc * 32 + 8 * r2 + 4 * g2;
            *reinterpret_cast<v4bf*>(Ol + (wid * 32 + l31) * 72 + d0) = w;
        }
    __syncthreads();

    const int b = bh >> 4, h = bh & 15;
    #pragma unroll
    for (int p = 0; p < 4; ++p) {
        const int row = p * 32 + (tid >> 3);
        const v8bf w = *reinterpret_cast<const v8bf*>(Ol + row * 72 + (tid & 7) * 8);
        *reinterpret_cast<v8bf*>(ao + (size_t)(b * 2048 + l0 + row) * 1024 + h * 64 + (tid & 7) * 8) = w;
    }
}

extern "C" void kernel_launch(void* const* d_in, const int* in_sizes, int n_in,
                              void* d_out, int out_size, void* d_ws, size_t ws_size,
                              hipStream_t stream) {
    (void)in_sizes; (void)n_in; (void)out_size; (void)ws_size;
    const float* query = (const float*)d_in[0];
    const float* key   = (const float*)d_in[1];
    const float* value = (const float*)d_in[2];
    const float* Wq    = (const float*)d_in[3];
    const float* bq    = (const float*)d_in[4];
    const float* Wk    = (const float*)d_in[5];
    const float* bk    = (const float*)d_in[6];
    const float* Wv    = (const float*)d_in[7];
    const float* bv    = (const float*)d_in[8];
    const float* Wo    = (const float*)d_in[9];
    const float* bo    = (const float*)d_in[10];
    const float* rel   = (const float*)d_in[11];
    float* out = (float*)d_out;

    __bf16* q_bf  = (__bf16*)d_ws;            // [32][2048][64]   8 MiB (prescaled)
    __bf16* k_bf  = q_bf + 4194304;           //                  8 MiB
    __bf16* vt_bf = k_bf + 4194304;           // [32][64][2048]   8 MiB
    __bf16* Wt4   = vt_bf + 4194304;          // 4x [1024][1024]  8 MiB
    __bf16* E_pad = Wt4 + 4194304;            // [2304][64]       0.28 MiB
    __bf16* aob   = E_pad + 147456;           // [4096][1024]     8 MiB

    const dim3 blk(256);

    cast_rel<<<144, blk, 0, stream>>>(rel, E_pad);
    transpose_cast_w4<<<dim3(16, 16, 4), blk, 0, stream>>>(Wq, Wk, Wv, Wo, Wt4);
    gemm_proj3<<<dim3(8, 32, 3), blk, 0, stream>>>(query, key, value, Wt4,
                                                   bq, bk, bv, q_bf, k_bf, vt_bf);
    attn_mfma<<<dim3(16, 32), blk, 0, stream>>>(q_bf, k_bf, vt_bf,
                                                E_pad + 128 * 64, aob);
    gemm_out<<<dim3(8, 32), blk, 0, stream>>>(aob, Wt4 + 3 * 1048576, bo, out);
}

// Round 13
// 186.971 us; speedup vs baseline: 1.7111x; 1.0004x over previous
//
#include <hip/hip_runtime.h>
#include <hip/hip_bf16.h>

// B=2, L=2048, D=1024, H=16, DH=64, M=2048
// logits[l,m] = (q[l].k[m] + (m<=l ? q[l].E[2047+m-l] : 0)) / 8, E[j]=rel[j+1]
// softmax over all m (no causal mask), out = (attn@v reshaped) @ Wo + bo
// Round 13: r12 + K/V double-buffered in LDS -> ONE barrier per m-step.
// (LDS exactly 80KB -> still 2 blocks/CU.) Single-variable change vs r12.

typedef __bf16 v8bf __attribute__((ext_vector_type(8)));
typedef __bf16 v4bf __attribute__((ext_vector_type(4)));
typedef float f32x4 __attribute__((ext_vector_type(4)));
typedef float f32x16 __attribute__((ext_vector_type(16)));

#define MFMA16(A,B,C) __builtin_amdgcn_mfma_f32_16x16x32_bf16((A),(B),(C),0,0,0)
#define MFMA32(A,B,C) __builtin_amdgcn_mfma_f32_32x32x16_bf16((A),(B),(C),0,0,0)

constexpr float kQScale = 0.1803368801111244f;   // log2(e)/8

// ---------------- rel -> E_pad [2304][64] bf16: rows 128..2175 = rel[1:2049], else 0
__global__ __launch_bounds__(256)
void cast_rel(const float* __restrict__ rel, __bf16* __restrict__ E)
{
    const int i = blockIdx.x * 256 + threadIdx.x;   // 4-elem units, 2304*16 total
    if (i >= 2304 * 16) return;
    const int base = i * 4;
    const int row = base >> 6;
    const int prow = row - 128;
    v4bf o;
    if (prow >= 0 && prow < 2048) {
        const float4 v = *reinterpret_cast<const float4*>(&rel[(size_t)(prow + 1) * 64 + (base & 63)]);
        o[0] = (__bf16)v.x; o[1] = (__bf16)v.y; o[2] = (__bf16)v.z; o[3] = (__bf16)v.w;
    } else {
        o[0] = (__bf16)0.f; o[1] = (__bf16)0.f; o[2] = (__bf16)0.f; o[3] = (__bf16)0.f;
    }
    *reinterpret_cast<v4bf*>(&E[base]) = o;
}

// ---------------- 4x W [1024][1024] fp32 -> Wt [n][k] bf16 (transpose+cast) ----------------
__global__ __launch_bounds__(256)
void transpose_cast_w4(const float* __restrict__ W0, const float* __restrict__ W1,
                       const float* __restrict__ W2, const float* __restrict__ W3,
                       __bf16* __restrict__ Wt4)
{
    __shared__ float tile[64][65];
    const int z = blockIdx.z;
    const float* W = (z == 0) ? W0 : (z == 1) ? W1 : (z == 2) ? W2 : W3;
    __bf16* Wt = Wt4 + (size_t)z * 1048576;
    const int r0 = blockIdx.y * 64, c0 = blockIdx.x * 64;
    const int tr = threadIdx.x >> 4;
    const int tc = (threadIdx.x & 15) * 4;
    #pragma unroll
    for (int p = 0; p < 4; ++p) {
        const int r = tr + p * 16;
        const float4 v = *reinterpret_cast<const float4*>(&W[(size_t)(r0 + r) * 1024 + c0 + tc]);
        tile[r][tc + 0] = v.x; tile[r][tc + 1] = v.y; tile[r][tc + 2] = v.z; tile[r][tc + 3] = v.w;
    }
    __syncthreads();
    #pragma unroll
    for (int p = 0; p < 4; ++p) {
        const int cr = tr + p * 16;
        v4bf o;
        o[0] = (__bf16)tile[tc + 0][cr];
        o[1] = (__bf16)tile[tc + 1][cr];
        o[2] = (__bf16)tile[tc + 2][cr];
        o[3] = (__bf16)tile[tc + 3][cr];
        *reinterpret_cast<v4bf*>(&Wt[(size_t)(c0 + cr) * 1024 + r0 + tc]) = o;
    }
}

// ---------------- bf16 MFMA GEMM body: C = A[4096x1024] @ Wt^T + bias, 128x128 tile ----
// mode 0: fp32 flat out; mode 1: bf16 heads [bh][l][64] (scaled by oscale);
// mode 2: bf16 [bh][dh][2048]
template <bool ABF16>
__device__ __forceinline__
void gemm_body(const float* __restrict__ Af, const __bf16* __restrict__ Ab,
               const __bf16* __restrict__ Wt, const float* __restrict__ bias,
               float* __restrict__ Cf, __bf16* __restrict__ Cb, int mode,
               float oscale, int bx, int by)
{
    __shared__ __bf16 As[2][128 * 64];
    __shared__ __bf16 Ws[2][128 * 64];
    const int tid = threadIdx.x;
    const int wid = tid >> 6, lane = tid & 63, g = lane >> 4, li = lane & 15;
    const int r0 = by * 128, c0 = bx * 128;
    const int wr = wid >> 1, wc = wid & 1;        // wave quadrant (64x64)
    const int sr = tid >> 3, sb = tid & 7;

    f32x4 acc[4][4];
    #pragma unroll
    for (int a = 0; a < 4; ++a)
        #pragma unroll
        for (int b2 = 0; b2 < 4; ++b2) acc[a][b2] = f32x4{0.f, 0.f, 0.f, 0.f};

    v8bf areg[4], wreg[4];

    auto loadA = [&](int p, int kt) -> v8bf {
        if constexpr (ABF16) {
            return *reinterpret_cast<const v8bf*>(&Ab[(size_t)(r0 + sr + 32 * p) * 1024 + kt + sb * 8]);
        } else {
            const float* ar = &Af[(size_t)(r0 + sr + 32 * p) * 1024 + kt + sb * 8];
            const float4 f0 = *reinterpret_cast<const float4*>(ar);
            const float4 f1 = *reinterpret_cast<const float4*>(ar + 4);
            v8bf a8;
            a8[0] = (__bf16)f0.x; a8[1] = (__bf16)f0.y; a8[2] = (__bf16)f0.z; a8[3] = (__bf16)f0.w;
            a8[4] = (__bf16)f1.x; a8[5] = (__bf16)f1.y; a8[6] = (__bf16)f1.z; a8[7] = (__bf16)f1.w;
            return a8;
        }
    };
    auto loadW = [&](int p, int kt) -> v8bf {
        return *reinterpret_cast<const v8bf*>(&Wt[(size_t)(c0 + sr + 32 * p) * 1024 + kt + sb * 8]);
    };

    #pragma unroll
    for (int p = 0; p < 4; ++p) { areg[p] = loadA(p, 0); wreg[p] = loadW(p, 0); }
    #pragma unroll
    for (int p = 0; p < 4; ++p) {
        const int row = sr + 32 * p;
        *reinterpret_cast<v8bf*>(&As[0][row * 64 + ((sb ^ (row & 7)) << 3)]) = areg[p];
        *reinterpret_cast<v8bf*>(&Ws[0][row * 64 + ((sb ^ (row & 7)) << 3)]) = wreg[p];
    }
    __syncthreads();

    for (int ki = 0; ki < 16; ++ki) {
        const int cur = ki & 1;
        if (ki < 15) {
            const int kt = (ki + 1) * 64;
            #pragma unroll
            for (int p = 0; p < 4; ++p) { areg[p] = loadA(p, kt); wreg[p] = loadW(p, kt); }
        }
        #pragma unroll
        for (int ks = 0; ks < 2; ++ks) {
            v8bf af[4], bfr[4];
            #pragma unroll
            for (int fm = 0; fm < 4; ++fm) {
                const int row = wr * 64 + fm * 16 + li;
                af[fm] = *reinterpret_cast<const v8bf*>(
                    &As[cur][row * 64 + (((ks * 4 + g) ^ (row & 7)) << 3)]);
            }
            #pragma unroll
            for (int fn = 0; fn < 4; ++fn) {
                const int row = wc * 64 + fn * 16 + li;
                bfr[fn] = *reinterpret_cast<const v8bf*>(
                    &Ws[cur][row * 64 + (((ks * 4 + g) ^ (row & 7)) << 3)]);
            }
            __builtin_amdgcn_s_setprio(1);
            #pragma unroll
            for (int fm = 0; fm < 4; ++fm)
                #pragma unroll
                for (int fn = 0; fn < 4; ++fn)
                    acc[fm][fn] = MFMA16(af[fm], bfr[fn], acc[fm][fn]);
            __builtin_amdgcn_s_setprio(0);
        }
        if (ki < 15) {
            const int nxt = cur ^ 1;
            #pragma unroll
            for (int p = 0; p < 4; ++p) {
                const int row = sr + 32 * p;
                *reinterpret_cast<v8bf*>(&As[nxt][row * 64 + ((sb ^ (row & 7)) << 3)]) = areg[p];
                *reinterpret_cast<v8bf*>(&Ws[nxt][row * 64 + ((sb ^ (row & 7)) << 3)]) = wreg[p];
            }
        }
        __syncthreads();
    }

    #pragma unroll
    for (int fn = 0; fn < 4; ++fn) {
        const int col = c0 + wc * 64 + fn * 16 + li;
        const float bb = bias[col];
        #pragma unroll
        for (int fm = 0; fm < 4; ++fm) {
            if (mode == 2) {
                const int row = r0 + wr * 64 + fm * 16 + 4 * g;
                const int b = row >> 11, l = row & 2047;
                const int h = col >> 6, dh = col & 63;
                v4bf pk;
                #pragma unroll
                for (int reg = 0; reg < 4; ++reg)
                    pk[reg] = (__bf16)(acc[fm][fn][reg] + bb);
                *reinterpret_cast<v4bf*>(&Cb[((size_t)((b * 16 + h) * 64 + dh)) * 2048 + l]) = pk;
            } else {
                #pragma unroll
                for (int reg = 0; reg < 4; ++reg) {
                    const int row = r0 + wr * 64 + fm * 16 + 4 * g + reg;
                    const float val = acc[fm][fn][reg] + bb;
                    if (mode == 0) {
                        Cf[(size_t)row * 1024 + col] = val;
                    } else {
                        const int b = row >> 11, l = row & 2047, h = col >> 6, dh = col & 63;
                        Cb[((size_t)(b * 16 + h) * 2048 + l) * 64 + dh] = (__bf16)(val * oscale);
                    }
                }
            }
        }
    }
}

// XCD remap for (8 x-tiles, 32 y-panels): each XCD gets 4 y-panels x 8 x-tiles
// so the A row-panel is fetched into one XCD's L2 once.
__device__ __forceinline__ void xcd_remap_gemm(int& bx, int& by)
{
    const int flat = by * 8 + bx;          // 0..255
    const int xcd = flat & 7;
    const int idx = flat >> 3;             // 0..31
    by = xcd * 4 + (idx & 3);
    bx = idx >> 2;
}

__global__ __launch_bounds__(256)
void gemm_proj3(const float* __restrict__ Aq, const float* __restrict__ Ak,
                const float* __restrict__ Av, const __bf16* __restrict__ Wt4,
                const float* __restrict__ bq, const float* __restrict__ bk,
                const float* __restrict__ bv, __bf16* __restrict__ qo,
                __bf16* __restrict__ ko, __bf16* __restrict__ vto)
{
    const int z = blockIdx.z;
    const float* A = (z == 0) ? Aq : (z == 1) ? Ak : Av;
    const __bf16* Wt = Wt4 + (size_t)z * 1048576;
    const float* bias = (z == 0) ? bq : (z == 1) ? bk : bv;
    __bf16* Cb = (z == 0) ? qo : (z == 1) ? ko : vto;
    const float osc = (z == 0) ? kQScale : 1.0f;
    int bx = blockIdx.x, by = blockIdx.y;
    xcd_remap_gemm(bx, by);
    gemm_body<false>(A, nullptr, Wt, bias, nullptr, Cb, (z == 2) ? 2 : 1, osc, bx, by);
}

__global__ __launch_bounds__(256)
void gemm_out(const __bf16* __restrict__ A, const __bf16* __restrict__ Wt,
              const float* __restrict__ bias, float* __restrict__ C)
{
    int bx = blockIdx.x, by = blockIdx.y;
    xcd_remap_gemm(bx, by);
    gemm_body<true>(nullptr, A, Wt, bias, C, nullptr, 0, 1.0f, bx, by);
}

// ---------------- fused attention (r12 + K/V dbuf, one barrier/step) ----------------
// q,k: [32][2048][64] bf16 (q prescaled); vt: [32][64][2048] bf16;
// Ep: padded E (rows -128..2175 valid); ao: [4096][1024] bf16.
// Block = 256 thr = 4 waves x 32 q-rows; 32 m-steps of 64; K/V double-buffered
// in LDS (ONE barrier/step); per-wave T ring [32][128] and P strip [32][64],
// XOR-block-swizzled: phys = base + (col ^ ((l31&7)<<3)). LDS = 80 KiB exactly.
__global__ __launch_bounds__(256, 2)
void attn_mfma(const __bf16* __restrict__ q, const __bf16* __restrict__ k,
               const __bf16* __restrict__ vt, const __bf16* __restrict__ Ep,
               __bf16* __restrict__ ao)
{
    __shared__ __bf16 Kl[2][64 * 64];     // dbuf [m][d], 16B-block XOR swizzle (16K)
    __shared__ __bf16 Vl[2][64 * 64];     // dbuf [d][m], swizzled (16K)
    __shared__ __bf16 Tl[4][32 * 128];    // per-wave T ring, XOR-swizzled (32K)
    __shared__ __bf16 Pl[4][32 * 64];     // per-wave P, XOR-swizzled (16K)

    const int tid = threadIdx.x;
    const int wid = tid >> 6;
    const int lane = tid & 63;
    const int l31 = lane & 31;
    const int g2 = lane >> 5;
    const int xsh = (l31 & 7) << 3;       // XOR pattern (bits 3-5)

    // XCD-aware remap: all 16 q-tiles of a bh land on one XCD (K/V L2 locality)
    const int flat = blockIdx.y * 16 + blockIdx.x;
    const int jj_ = flat >> 3;
    const int bh = (flat & 7) * 4 + (jj_ >> 4);
    const int qt = jj_ & 15;

    const int l0 = qt * 128;
    const int lw0 = l0 + wid * 32;            // wave's first q-row
    const size_t hbase = (size_t)bh * (2048 * 64);
    const __bf16* qp = q + hbase;
    const __bf16* kp = k + hbase;
    const __bf16* vtp = vt + hbase;           // [64][2048]
    const int wb0 = 1984 - l0 - 32 * wid;     // per-wave e-window base at t=0

    __bf16* Tw = &Tl[wid][0];
    __bf16* Pw = &Pl[wid][0];

    // Q B-fragments (col = l lane-local), prescaled by log2e/8 at projection
    v8bf qf[4];
    {
        const __bf16* qrow = qp + (size_t)(lw0 + l31) * 64 + g2 * 8;
        qf[0] = *reinterpret_cast<const v8bf*>(qrow);
        qf[1] = *reinterpret_cast<const v8bf*>(qrow + 16);
        qf[2] = *reinterpret_cast<const v8bf*>(qrow + 32);
        qf[3] = *reinterpret_cast<const v8bf*>(qrow + 48);
    }

    const int sr = tid >> 3, sb = tid & 7;

    auto eload = [&](int baseRow, v8bf eb[8]) {
        #pragma unroll
        for (int jc = 0; jc < 2; ++jc)
            #pragma unroll
            for (int ks = 0; ks < 4; ++ks)
                eb[jc * 4 + ks] = *reinterpret_cast<const v8bf*>(
                    Ep + (long)(baseRow + jc * 32 + l31) * 64 + ks * 16 + g2 * 8);
    };

    // T-GEMM: T[l][colBase + j_local] = q[l] . E[rows]; store XOR-swizzled
    auto tgemm = [&](const v8bf eb[8], int colBase) {
        #pragma unroll
        for (int jc = 0; jc < 2; ++jc) {
            f32x16 tacc;
            #pragma unroll
            for (int r = 0; r < 16; ++r) tacc[r] = 0.f;
            __builtin_amdgcn_s_setprio(1);
            #pragma unroll
            for (int ks = 0; ks < 4; ++ks)
                tacc = MFMA32(eb[jc * 4 + ks], qf[ks], tacc);
            __builtin_amdgcn_s_setprio(0);
            #pragma unroll
            for (int r2 = 0; r2 < 4; ++r2) {
                v4bf w;
                w[0] = (__bf16)tacc[4 * r2 + 0]; w[1] = (__bf16)tacc[4 * r2 + 1];
                w[2] = (__bf16)tacc[4 * r2 + 2]; w[3] = (__bf16)tacc[4 * r2 + 3];
                const int col = colBase + jc * 32 + 8 * r2 + 4 * g2;
                *reinterpret_cast<v4bf*>(Tw + l31 * 128 + (col ^ xsh)) = w;
            }
        }
    };

    // ---- prologue: stage K/V tile 0 into buf 0; T window [wb0, wb0+128) ----
    {
        const v8bf k0a = *reinterpret_cast<const v8bf*>(kp + (size_t)sr * 64 + sb * 8);
        const v8bf k0b = *reinterpret_cast<const v8bf*>(kp + (size_t)(sr + 32) * 64 + sb * 8);
        const v8bf v0a = *reinterpret_cast<const v8bf*>(vtp + (size_t)sr * 2048 + sb * 8);
        const v8bf v0b = *reinterpret_cast<const v8bf*>(vtp + (size_t)(sr + 32) * 2048 + sb * 8);
        v8bf ebA[8], ebB[8];
        eload(wb0, ebA);
        eload(wb0 + 64, ebB);
        *reinterpret_cast<v8bf*>(&Kl[0][sr * 64 + ((sb ^ (sr & 7)) << 3)]) = k0a;
        *reinterpret_cast<v8bf*>(&Kl[0][(sr + 32) * 64 + ((sb ^ (sr & 7)) << 3)]) = k0b;
        *reinterpret_cast<v8bf*>(&Vl[0][sr * 64 + ((sb ^ (sr & 7)) << 3)]) = v0a;
        *reinterpret_cast<v8bf*>(&Vl[0][(sr + 32) * 64 + ((sb ^ (sr & 7)) << 3)]) = v0b;
        __syncthreads();
        tgemm(ebA, 0);
        tgemm(ebB, 64);
    }

    f32x16 oacc[2];
    #pragma unroll
    for (int dc = 0; dc < 2; ++dc)
        #pragma unroll
        for (int r = 0; r < 16; ++r) oacc[dc][r] = 0.f;
    float lrow = 0.f;

    for (int t = 0; t < 32; ++t) {
        const int m0 = t * 64;
        const int cur = t & 1, nxt = cur ^ 1;
        const bool lastT = (t == 31);
        const bool needRel = (m0 <= lw0 + 31);
        const bool fullAdd = (m0 + 63 <= lw0);
        const bool needTnext = (m0 + 64 <= lw0 + 31);
        const int lob = 64 * (t & 1);

        // E loads for next window's hi block
        v8bf ebN[8];
        if (needTnext) eload(wb0 + 64 * t + 128, ebN);

        // K/V prefetch for t+1 (written to buf[nxt] after PV; one barrier/step)
        v8bf kra, krb, vra, vrb;
        if (!lastT) {
            const int m1 = m0 + 64;
            kra = *reinterpret_cast<const v8bf*>(kp + (size_t)(m1 + sr) * 64 + sb * 8);
            krb = *reinterpret_cast<const v8bf*>(kp + (size_t)(m1 + sr + 32) * 64 + sb * 8);
            vra = *reinterpret_cast<const v8bf*>(vtp + (size_t)sr * 2048 + m1 + sb * 8);
            vrb = *reinterpret_cast<const v8bf*>(vtp + (size_t)(sr + 32) * 2048 + m1 + sb * 8);
        }

        // ---- QK^T (swapped: D[col=l][row=m]) + rel gather + exp + pack, per 32-m chunk
        #pragma unroll
        for (int mc = 0; mc < 2; ++mc) {
            f32x16 sacc;
            #pragma unroll
            for (int r = 0; r < 16; ++r) sacc[r] = 0.f;
            __builtin_amdgcn_s_setprio(1);
            #pragma unroll
            for (int ks = 0; ks < 4; ++ks) {
                const int row = mc * 32 + l31;
                const v8bf kb = *reinterpret_cast<const v8bf*>(
                    &Kl[cur][row * 64 + (((2 * ks + g2) ^ (l31 & 7)) << 3)]);
                sacc = MFMA32(kb, qf[ks], sacc);
            }
            __builtin_amdgcn_s_setprio(0);

            if (needRel) {
                const int cb = 63 - l31 + lob;
                if (fullAdd) {
                    #pragma unroll
                    for (int r2 = 0; r2 < 4; ++r2)
                        #pragma unroll
                        for (int i2 = 0; i2 < 4; ++i2) {
                            const int mtl = mc * 32 + 8 * r2 + 4 * g2 + i2;
                            const int c = (cb + mtl) & 127;
                            sacc[4 * r2 + i2] += (float)Tw[l31 * 128 + (c ^ xsh)];
                        }
                } else {
                    const int R = lw0 + l31 - m0;      // add iff m_tl <= R
                    #pragma unroll
                    for (int r2 = 0; r2 < 4; ++r2)
                        #pragma unroll
                        for (int i2 = 0; i2 < 4; ++i2) {
                            const int mtl = mc * 32 + 8 * r2 + 4 * g2 + i2;
                            const int c = (cb + mtl) & 127;
                            const float tv = (float)Tw[l31 * 128 + (c ^ xsh)];
                            sacc[4 * r2 + i2] += (mtl <= R) ? tv : 0.f;
                        }
                }
            }

            // exp2 + row-sum + pack P (bf16) into per-wave LDS (XOR-swizzled)
            #pragma unroll
            for (int jj = 0; jj < 4; ++jj) {
                const float p0 = exp2f(sacc[4 * jj + 0]);
                const float p1 = exp2f(sacc[4 * jj + 1]);
                const float p2 = exp2f(sacc[4 * jj + 2]);
                const float p3 = exp2f(sacc[4 * jj + 3]);
                lrow += (p0 + p1) + (p2 + p3);
                v4bf w;
                w[0] = (__bf16)p0; w[1] = (__bf16)p1; w[2] = (__bf16)p2; w[3] = (__bf16)p3;
                const int col = mc * 32 + 8 * jj + 4 * g2;
                *reinterpret_cast<v4bf*>(Pw + l31 * 64 + (col ^ xsh)) = w;
            }
        }

        // ---- new-hi T block for t+1 (after gather read the retiring lo cols) ----
        if (needTnext) tgemm(ebN, lob);

        // ---- O += P V  (A = V^T rows d, B = P cols l) ----
        #pragma unroll
        for (int ks = 0; ks < 4; ++ks) {
            const v8bf pa = *reinterpret_cast<const v8bf*>(
                Pw + l31 * 64 + ((ks * 16 + g2 * 8) ^ xsh));
            __builtin_amdgcn_s_setprio(1);
            #pragma unroll
            for (int dc = 0; dc < 2; ++dc) {
                const int row = dc * 32 + l31;
                const v8bf vb = *reinterpret_cast<const v8bf*>(
                    &Vl[cur][row * 64 + (((2 * ks + g2) ^ (l31 & 7)) << 3)]);
                oacc[dc] = MFMA32(vb, pa, oacc[dc]);
            }
            __builtin_amdgcn_s_setprio(0);
        }

        // ---- write prefetched tiles to buf[nxt]; ONE barrier per step ----
        if (!lastT) {
            *reinterpret_cast<v8bf*>(&Kl[nxt][sr * 64 + ((sb ^ (sr & 7)) << 3)]) = kra;
            *reinterpret_cast<v8bf*>(&Kl[nxt][(sr + 32) * 64 + ((sb ^ (sr & 7)) << 3)]) = krb;
            *reinterpret_cast<v8bf*>(&Vl[nxt][sr * 64 + ((sb ^ (sr & 7)) << 3)]) = vra;
            *reinterpret_cast<v8bf*>(&Vl[nxt][(sr + 32) * 64 + ((sb ^ (sr & 7)) << 3)]) = vrb;
        }
        __syncthreads();
    }

    // ---- epilogue: normalize, stage O in LDS (alias Tl), coalesced bf16 store ----
    lrow += __shfl_xor(lrow, 32);
    const float inv = 1.0f / lrow;

    __syncthreads();
    __bf16* Ol = &Tl[0][0];                   // [128][72] bf16 (18.4K <= 32K)
    #pragma unroll
    for (int dc = 0; dc < 2; ++dc)
        #pragma unroll
        for (int r2 = 0; r2 < 4; ++r2) {
            v4bf w;
            w[0] = (__bf16)(oacc[dc][4 * r2 + 0] * inv);
            w[1] = (__bf16)(oacc[dc][4 * r2 + 1] * inv);
            w[2] = (__bf16)(oacc[dc][4 * r2 + 2] * inv);
            w[3] = (__bf16)(oacc[dc][4 * r2 + 3] * inv);
            const int d0 = dc * 32 + 8 * r2 + 4 * g2;
            *reinterpret_cast<v4bf*>(Ol + (wid * 32 + l31) * 72 + d0) = w;
        }
    __syncthreads();

    const int b = bh >> 4, h = bh & 15;
    #pragma unroll
    for (int p = 0; p < 4; ++p) {
        const int row = p * 32 + (tid >> 3);
        const v8bf w = *reinterpret_cast<const v8bf*>(Ol + row * 72 + (tid & 7) * 8);
        *reinterpret_cast<v8bf*>(ao + (size_t)(b * 2048 + l0 + row) * 1024 + h * 64 + (tid & 7) * 8) = w;
    }
}

extern "C" void kernel_launch(void* const* d_in, const int* in_sizes, int n_in,
                              void* d_out, int out_size, void* d_ws, size_t ws_size,
                              hipStream_t stream) {
    (void)in_sizes; (void)n_in; (void)out_size; (void)ws_size;
    const float* query = (const float*)d_in[0];
    const float* key   = (const float*)d_in[1];
    const float* value = (const float*)d_in[2];
    const float* Wq    = (const float*)d_in[3];
    const float* bq    = (const float*)d_in[4];
    const float* Wk    = (const float*)d_in[5];
    const float* bk    = (const float*)d_in[6];
    const float* Wv    = (const float*)d_in[7];
    const float* bv    = (const float*)d_in[8];
    const float* Wo    = (const float*)d_in[9];
    const float* bo    = (const float*)d_in[10];
    const float* rel   = (const float*)d_in[11];
    float* out = (float*)d_out;

    __bf16* q_bf  = (__bf16*)d_ws;            // [32][2048][64]   8 MiB (prescaled)
    __bf16* k_bf  = q_bf + 4194304;           //                  8 MiB
    __bf16* vt_bf = k_bf + 4194304;           // [32][64][2048]   8 MiB
    __bf16* Wt4   = vt_bf + 4194304;          // 4x [1024][1024]  8 MiB
    __bf16* E_pad = Wt4 + 4194304;            // [2304][64]       0.28 MiB
    __bf16* aob   = E_pad + 147456;           // [4096][1024]     8 MiB

    const dim3 blk(256);

    cast_rel<<<144, blk, 0, stream>>>(rel, E_pad);
    transpose_cast_w4<<<dim3(16, 16, 4), blk, 0, stream>>>(Wq, Wk, Wv, Wo, Wt4);
    gemm_proj3<<<dim3(8, 32, 3), blk, 0, stream>>>(query, key, value, Wt4,
                                                   bq, bk, bv, q_bf, k_bf, vt_bf);
    attn_mfma<<<dim3(16, 32), blk, 0, stream>>>(q_bf, k_bf, vt_bf,
                                                E_pad + 128 * 64, aob);
    gemm_out<<<dim3(8, 32), blk, 0, stream>>>(aob, Wt4 + 3 * 1048576, bo, out);
}